// Round 1
// baseline (366.258 us; speedup 1.0000x reference)
//
#include <hip/hip_runtime.h>
#include <hip/hip_bf16.h>
#include <math.h>

// Problem constants
#define NBH 32     // B*KVH = 4*8
#define HPKN 4
#define DN 128
#define SEQKV 4096
#define SEQN 4097
#define RANKN 32
#define KSEL 516   // K + SINK = 512 + 4
#define SINKN 4
#define LOCALK 128 // masked-local region starts at SEQKV - LOCALK = 3968

// ---------------------------------------------------------------------------
// Kernel 1: per (b,h): top-32 dims of sum_p |q|, scale, pre-scaled q_proj,
// and the current-token (s=4096) approximate score.
// ---------------------------------------------------------------------------
__global__ __launch_bounds__(128) void k1_prep(
    const float* __restrict__ q, const float* __restrict__ key,
    const float* __restrict__ lm,
    float* __restrict__ qp_scaled, int* __restrict__ sidx_g,
    float* __restrict__ scores) {
  int bh = blockIdx.x;
  int b = bh >> 3, h = bh & 7;
  int d = threadIdx.x;
  __shared__ float qv[4][128];
  __shared__ float absq[128];
  __shared__ int sel[RANKN];
  __shared__ float red[128];
  __shared__ float scale_s[4];

  float a = 0.f;
  for (int p = 0; p < 4; ++p) {
    float val = q[((b * 32 + h * 4 + p) << 7) + d];
    qv[p][d] = val;
    a += fabsf(val);
  }
  absq[d] = a;
  __syncthreads();

  // rank of my dim among 128 (desc value, asc index tiebreak)
  int rank = 0;
  for (int e = 0; e < 128; ++e) {
    float ae = absq[e];
    rank += (ae > a) || (ae == a && e < d);
  }
  if (rank < RANKN) sel[rank] = d;
  __syncthreads();

  for (int p = 0; p < 4; ++p) {
    red[d] = fabsf(qv[p][d]);
    __syncthreads();
    for (int s = 64; s > 0; s >>= 1) { if (d < s) red[d] += red[d + s]; __syncthreads(); }
    float full = red[0];
    __syncthreads();
    red[d] = (d < RANKN) ? fabsf(qv[p][sel[d]]) : 0.f;
    __syncthreads();
    for (int s = 64; s > 0; s >>= 1) { if (d < s) red[d] += red[d + s]; __syncthreads(); }
    if (d == 0) scale_s[p] = sqrtf(red[0] / full * 128.f);
    __syncthreads();
    if (d < RANKN) qp_scaled[(bh * 4 + p) * RANKN + d] = qv[p][sel[d]] / scale_s[p];
    __syncthreads();
  }
  if (d < RANKN) sidx_g[bh * RANKN + d] = sel[d];

  // approximate score at s = 4096 (current key)
  float keyv = (d < RANKN) ? key[bh * 128 + sel[d]] : 0.f;
  for (int p = 0; p < 4; ++p) {
    red[d] = (d < RANKN) ? (qv[p][sel[d]] / scale_s[p]) * keyv : 0.f;
    __syncthreads();
    for (int s = 64; s > 0; s >>= 1) { if (d < s) red[d] += red[d + s]; __syncthreads(); }
    if (d == 0)
      scores[(size_t)(bh * 4 + p) * SEQN + SEQKV] =
          red[0] + lm[(size_t)(b * 32 + h * 4 + p) * SEQN + SEQKV];
    __syncthreads();
  }
}

// ---------------------------------------------------------------------------
// Kernel 2: approximate scores over history, and per-position sum over p.
// grid (8 chunks of 512 positions, 32 bh), block 256.
// ---------------------------------------------------------------------------
__global__ __launch_bounds__(256) void k2_scores(
    const float* __restrict__ skey, const float* __restrict__ lm,
    const float* __restrict__ qp_scaled, const int* __restrict__ sidx_g,
    float* __restrict__ scores, float* __restrict__ tk) {
  int bh = blockIdx.y;
  int b = bh >> 3, h = bh & 7;
  int s0 = blockIdx.x << 9;
  int t = threadIdx.x;
  __shared__ float qp[4][RANKN];
  __shared__ int sel[RANKN];
  if (t < 128) qp[t >> 5][t & 31] = qp_scaled[bh * 128 + t];
  if (t < RANKN) sel[t] = sidx_g[bh * RANKN + t];
  __syncthreads();
  const float* kb = skey + (size_t)bh * 128 * 4096;
  float a00 = 0, a01 = 0, a02 = 0, a03 = 0;
  float a10 = 0, a11 = 0, a12 = 0, a13 = 0;
#pragma unroll 4
  for (int r = 0; r < RANKN; ++r) {
    const float* row = kb + ((size_t)sel[r] << 12) + s0;
    float k0 = row[t];
    float k1 = row[t + 256];
    float q0 = qp[0][r], q1 = qp[1][r], q2 = qp[2][r], q3 = qp[3][r];
    a00 += q0 * k0; a01 += q1 * k0; a02 += q2 * k0; a03 += q3 * k0;
    a10 += q0 * k1; a11 += q1 * k1; a12 += q2 * k1; a13 += q3 * k1;
  }
  float acc0[4] = {a00, a01, a02, a03};
  float acc1[4] = {a10, a11, a12, a13};
  {
    int s = s0 + t;
    float sum = 0;
    for (int p = 0; p < 4; ++p) {
      float sc = acc0[p] + lm[(size_t)(b * 32 + h * 4 + p) * SEQN + s];
      scores[(size_t)(bh * 4 + p) * SEQN + s] = sc;
      sum += sc;
    }
    tk[(bh << 12) + s] = sum;
  }
  {
    int s = s0 + t + 256;
    float sum = 0;
    for (int p = 0; p < 4; ++p) {
      float sc = acc1[p] + lm[(size_t)(b * 32 + h * 4 + p) * SEQN + s];
      scores[(size_t)(bh * 4 + p) * SEQN + s] = sc;
      sum += sc;
    }
    tk[(bh << 12) + s] = sum;
  }
}

// ---------------------------------------------------------------------------
// Kernel 3: exact jax.lax.top_k(516) order via full bitonic sort of 4096
// 64-bit keys (sortable-float, ~index). Masked positions forced to +inf.
// ---------------------------------------------------------------------------
__global__ __launch_bounds__(1024) void k3_topk(
    const float* __restrict__ tk, int* __restrict__ indices) {
  int bh = blockIdx.x;
  __shared__ unsigned long long keys[4096];
  int t = threadIdx.x;
  for (int s = t; s < 4096; s += 1024) {
    unsigned u;
    if (s < SINKN || s >= SEQKV - LOCALK) {
      u = 0xFF800000u;  // sortable(+inf)
    } else {
      float v = tk[(bh << 12) + s];
      unsigned b = __float_as_uint(v);
      u = (b & 0x80000000u) ? ~b : (b | 0x80000000u);
    }
    keys[s] = ((unsigned long long)u << 32) | (unsigned)(~s);
  }
  __syncthreads();
  for (int k = 2; k <= 4096; k <<= 1) {
    for (int j = k >> 1; j > 0; j >>= 1) {
      for (int i = t; i < 4096; i += 1024) {
        int ixj = i ^ j;
        if (ixj > i) {
          bool desc = ((i & k) == 0);
          unsigned long long a = keys[i], bb = keys[ixj];
          if ((a < bb) == desc) { keys[i] = bb; keys[ixj] = a; }
        }
      }
      __syncthreads();
    }
  }
  for (int j = t; j < KSEL; j += 1024)
    indices[bh * KSEL + j] = (int)(~((unsigned)(keys[j] & 0xFFFFFFFFu)));
}

// ---------------------------------------------------------------------------
// Kernel 4: softmax stats / kv_weight, gathered attention, outputs.
// grid 32 (bh), block 512 (4 p-groups x 128).
// ---------------------------------------------------------------------------
__global__ __launch_bounds__(512) void k4_attn(
    const float* __restrict__ q, const float* __restrict__ key,
    const float* __restrict__ value, const float* __restrict__ lm,
    const float* __restrict__ key_cpu, const float* __restrict__ value_cpu,
    const float* __restrict__ mean_v, const float* __restrict__ scores,
    const int* __restrict__ indices, float* __restrict__ out,
    float* __restrict__ out_w) {
  int bh = blockIdx.x;
  int b = bh >> 3, h = bh & 7;
  int t = threadIdx.x;
  int p = t >> 7, ld = t & 127;
  __shared__ float qs[512];
  __shared__ int sidx[KSEL];
  __shared__ float red[512];
  __shared__ float kvw_s[4];
  __shared__ float s2[4][520];
  __shared__ float wsh[4][520];

  qs[t] = q[((size_t)(b * 32 + h * 4) << 7) + t];
  for (int j = t; j < KSEL; j += 512) sidx[j] = indices[bh * KSEL + j];
  __syncthreads();

  const float* srow = scores + (size_t)(bh * 4 + p) * SEQN;
  // max over 4097
  float mx = -INFINITY;
  for (int s = ld; s < SEQN; s += 128) mx = fmaxf(mx, srow[s]);
  red[t] = mx; __syncthreads();
  for (int st = 64; st > 0; st >>= 1) {
    if (ld < st) red[t] = fmaxf(red[t], red[t + st]);
    __syncthreads();
  }
  float m = red[p << 7];
  __syncthreads();
  // total sum of exp
  float se = 0.f;
  for (int s = ld; s < SEQN; s += 128) se += expf(srow[s] - m);
  red[t] = se; __syncthreads();
  for (int st = 64; st > 0; st >>= 1) {
    if (ld < st) red[t] += red[t + st];
    __syncthreads();
  }
  float sumexp = red[p << 7];
  __syncthreads();
  // selected-mass
  float ss = 0.f;
  for (int j = ld; j < KSEL; j += 128) ss += expf(srow[sidx[j]] - m);
  red[t] = ss; __syncthreads();
  for (int st = 64; st > 0; st >>= 1) {
    if (ld < st) red[t] += red[t + st];
    __syncthreads();
  }
  if (ld == 0) kvw_s[p] = (red[p << 7] + expf(srow[SEQKV] - m)) / sumexp;
  __syncthreads();

  // phase B: s2[p][j] = q[p] . key_g[j] / sqrt(D) + lm_g
  int wave = t >> 6, lane = t & 63;
  const float rsqd = 0.08838834764831845f;  // 1/sqrt(128)
  for (int j = wave; j < KSEL + 1; j += 8) {
    const float* krow = (j < KSEL)
        ? key_cpu + (((size_t)bh << 12) + sidx[j]) * 128
        : key + (size_t)bh * 128;
    float k0 = krow[lane << 1], k1 = krow[(lane << 1) + 1];
    float p0 = qs[(lane << 1)] * k0 + qs[(lane << 1) + 1] * k1;
    float p1 = qs[128 + (lane << 1)] * k0 + qs[128 + (lane << 1) + 1] * k1;
    float p2 = qs[256 + (lane << 1)] * k0 + qs[256 + (lane << 1) + 1] * k1;
    float p3 = qs[384 + (lane << 1)] * k0 + qs[384 + (lane << 1) + 1] * k1;
    for (int off = 32; off > 0; off >>= 1) {
      p0 += __shfl_down(p0, off);
      p1 += __shfl_down(p1, off);
      p2 += __shfl_down(p2, off);
      p3 += __shfl_down(p3, off);
    }
    if (lane == 0) {
      int sj = (j < KSEL) ? sidx[j] : SEQKV;
      s2[0][j] = p0 * rsqd + lm[(size_t)(b * 32 + h * 4 + 0) * SEQN + sj];
      s2[1][j] = p1 * rsqd + lm[(size_t)(b * 32 + h * 4 + 1) * SEQN + sj];
      s2[2][j] = p2 * rsqd + lm[(size_t)(b * 32 + h * 4 + 2) * SEQN + sj];
      s2[3][j] = p3 * rsqd + lm[(size_t)(b * 32 + h * 4 + 3) * SEQN + sj];
    }
  }
  __syncthreads();

  // phase C: softmax over 517, times kv_weight; emit weights output
  float mx2 = -INFINITY;
  for (int j = ld; j < KSEL + 1; j += 128) mx2 = fmaxf(mx2, s2[p][j]);
  red[t] = mx2; __syncthreads();
  for (int st = 64; st > 0; st >>= 1) {
    if (ld < st) red[t] = fmaxf(red[t], red[t + st]);
    __syncthreads();
  }
  float m2 = red[p << 7];
  __syncthreads();
  float se2 = 0.f;
  for (int j = ld; j < KSEL + 1; j += 128) se2 += expf(s2[p][j] - m2);
  red[t] = se2; __syncthreads();
  for (int st = 64; st > 0; st >>= 1) {
    if (ld < st) red[t] += red[t + st];
    __syncthreads();
  }
  float inv = kvw_s[p] / red[p << 7];
  __syncthreads();
  for (int j = ld; j < KSEL + 1; j += 128) {
    float w = expf(s2[p][j] - m2) * inv;
    wsh[p][j] = w;
    out_w[(size_t)(b * 32 + h * 4 + p) * (KSEL + 1) + j] = w;
  }
  __syncthreads();

  // phase D: out[p][d] = sum_j w * V_g[j][d] + (1 - kvw) * mean_v_new[d]
  float acc = 0.f;
  for (int j = 0; j < KSEL; ++j)
    acc += wsh[p][j] * value_cpu[(((size_t)bh << 12) + sidx[j]) * 128 + ld];
  float vcur = value[(size_t)bh * 128 + ld];
  acc += wsh[p][KSEL] * vcur;
  float mvn = (mean_v[(size_t)bh * 128 + ld] * 4096.f + vcur) / 4097.f;
  out[(size_t)(b * 32 + h * 4 + p) * 128 + ld] = acc + (1.f - kvw_s[p]) * mvn;
}

// ---------------------------------------------------------------------------
extern "C" void kernel_launch(void* const* d_in, const int* in_sizes, int n_in,
                              void* d_out, int out_size, void* d_ws, size_t ws_size,
                              hipStream_t stream) {
  const float* query     = (const float*)d_in[0];
  const float* key       = (const float*)d_in[1];
  const float* value     = (const float*)d_in[2];
  const float* logmask   = (const float*)d_in[3];
  const float* key_cpu   = (const float*)d_in[4];
  const float* value_cpu = (const float*)d_in[5];
  const float* s_key_cpu = (const float*)d_in[6];
  const float* mean_v    = (const float*)d_in[7];

  float* out   = (float*)d_out;       // (4,32,1,128) = 16384 floats
  float* out_w = out + 16384;         // (4,32,1,517) = 66176 floats

  char* ws = (char*)d_ws;
  float* qp_scaled = (float*)ws;                  // 32*4*32 f = 16384 B
  int*   sidx      = (int*)(ws + 16384);          // 32*32 i   = 4096 B
  int*   indices   = (int*)(ws + 20480);          // 32*516 i  = 66048 B
  float* scores    = (float*)(ws + 86528);        // 32*4*4097 f = 2097664 B
  float* tk        = (float*)(ws + 2184192);      // 32*4096 f = 524288 B
  // total ws use: 2,708,480 bytes

  hipLaunchKernelGGL(k1_prep, dim3(NBH), dim3(128), 0, stream,
                     query, key, logmask, qp_scaled, sidx, scores);
  hipLaunchKernelGGL(k2_scores, dim3(8, NBH), dim3(256), 0, stream,
                     s_key_cpu, logmask, qp_scaled, sidx, scores, tk);
  hipLaunchKernelGGL(k3_topk, dim3(NBH), dim3(1024), 0, stream,
                     tk, indices);
  hipLaunchKernelGGL(k4_attn, dim3(NBH), dim3(512), 0, stream,
                     query, key, value, logmask, key_cpu, value_cpu,
                     mean_v, scores, indices, out, out_w);
}

// Round 2
// 287.160 us; speedup vs baseline: 1.2755x; 1.2755x over previous
//
#include <hip/hip_runtime.h>
#include <hip/hip_bf16.h>
#include <math.h>

// Problem constants
#define NBH 32     // B*KVH = 4*8
#define HPKN 4
#define DN 128
#define SEQKV 4096
#define SEQN 4097
#define RANKN 32
#define KSEL 516   // K + SINK = 512 + 4
#define SINKN 4
#define LOCALK 128 // masked-local region starts at SEQKV - LOCALK = 3968

// ---------------------------------------------------------------------------
// Kernel 1: per (b,h): top-32 dims of sum_p |q|, scale, pre-scaled q_proj,
// and the current-token (s=4096) approximate score.
// ---------------------------------------------------------------------------
__global__ __launch_bounds__(128) void k1_prep(
    const float* __restrict__ q, const float* __restrict__ key,
    const float* __restrict__ lm,
    float* __restrict__ qp_scaled, int* __restrict__ sidx_g,
    float* __restrict__ scores) {
  int bh = blockIdx.x;
  int b = bh >> 3, h = bh & 7;
  int d = threadIdx.x;
  __shared__ float qv[4][128];
  __shared__ float absq[128];
  __shared__ int sel[RANKN];
  __shared__ float red[128];
  __shared__ float scale_s[4];

  float a = 0.f;
  for (int p = 0; p < 4; ++p) {
    float val = q[((b * 32 + h * 4 + p) << 7) + d];
    qv[p][d] = val;
    a += fabsf(val);
  }
  absq[d] = a;
  __syncthreads();

  // rank of my dim among 128 (desc value, asc index tiebreak)
  int rank = 0;
  for (int e = 0; e < 128; ++e) {
    float ae = absq[e];
    rank += (ae > a) || (ae == a && e < d);
  }
  if (rank < RANKN) sel[rank] = d;
  __syncthreads();

  for (int p = 0; p < 4; ++p) {
    red[d] = fabsf(qv[p][d]);
    __syncthreads();
    for (int s = 64; s > 0; s >>= 1) { if (d < s) red[d] += red[d + s]; __syncthreads(); }
    float full = red[0];
    __syncthreads();
    red[d] = (d < RANKN) ? fabsf(qv[p][sel[d]]) : 0.f;
    __syncthreads();
    for (int s = 64; s > 0; s >>= 1) { if (d < s) red[d] += red[d + s]; __syncthreads(); }
    if (d == 0) scale_s[p] = sqrtf(red[0] / full * 128.f);
    __syncthreads();
    if (d < RANKN) qp_scaled[(bh * 4 + p) * RANKN + d] = qv[p][sel[d]] / scale_s[p];
    __syncthreads();
  }
  if (d < RANKN) sidx_g[bh * RANKN + d] = sel[d];

  // approximate score at s = 4096 (current key)
  float keyv = (d < RANKN) ? key[bh * 128 + sel[d]] : 0.f;
  for (int p = 0; p < 4; ++p) {
    red[d] = (d < RANKN) ? (qv[p][sel[d]] / scale_s[p]) * keyv : 0.f;
    __syncthreads();
    for (int s = 64; s > 0; s >>= 1) { if (d < s) red[d] += red[d + s]; __syncthreads(); }
    if (d == 0)
      scores[(size_t)(bh * 4 + p) * SEQN + SEQKV] =
          red[0] + lm[(size_t)(b * 32 + h * 4 + p) * SEQN + SEQKV];
    __syncthreads();
  }
}

// ---------------------------------------------------------------------------
// Kernel 2: approximate scores over history, and per-position sum over p.
// grid (8 chunks of 512 positions, 32 bh), block 256.
// ---------------------------------------------------------------------------
__global__ __launch_bounds__(256) void k2_scores(
    const float* __restrict__ skey, const float* __restrict__ lm,
    const float* __restrict__ qp_scaled, const int* __restrict__ sidx_g,
    float* __restrict__ scores, float* __restrict__ tk) {
  int bh = blockIdx.y;
  int b = bh >> 3, h = bh & 7;
  int s0 = blockIdx.x << 9;
  int t = threadIdx.x;
  __shared__ float qp[4][RANKN];
  __shared__ int sel[RANKN];
  if (t < 128) qp[t >> 5][t & 31] = qp_scaled[bh * 128 + t];
  if (t < RANKN) sel[t] = sidx_g[bh * RANKN + t];
  __syncthreads();
  const float* kb = skey + (size_t)bh * 128 * 4096;
  float a00 = 0, a01 = 0, a02 = 0, a03 = 0;
  float a10 = 0, a11 = 0, a12 = 0, a13 = 0;
#pragma unroll 4
  for (int r = 0; r < RANKN; ++r) {
    const float* row = kb + ((size_t)sel[r] << 12) + s0;
    float k0 = row[t];
    float k1 = row[t + 256];
    float q0 = qp[0][r], q1 = qp[1][r], q2 = qp[2][r], q3 = qp[3][r];
    a00 += q0 * k0; a01 += q1 * k0; a02 += q2 * k0; a03 += q3 * k0;
    a10 += q0 * k1; a11 += q1 * k1; a12 += q2 * k1; a13 += q3 * k1;
  }
  float acc0[4] = {a00, a01, a02, a03};
  float acc1[4] = {a10, a11, a12, a13};
  {
    int s = s0 + t;
    float sum = 0;
    for (int p = 0; p < 4; ++p) {
      float sc = acc0[p] + lm[(size_t)(b * 32 + h * 4 + p) * SEQN + s];
      scores[(size_t)(bh * 4 + p) * SEQN + s] = sc;
      sum += sc;
    }
    tk[(bh << 12) + s] = sum;
  }
  {
    int s = s0 + t + 256;
    float sum = 0;
    for (int p = 0; p < 4; ++p) {
      float sc = acc1[p] + lm[(size_t)(b * 32 + h * 4 + p) * SEQN + s];
      scores[(size_t)(bh * 4 + p) * SEQN + s] = sc;
      sum += sc;
    }
    tk[(bh << 12) + s] = sum;
  }
}

// ---------------------------------------------------------------------------
// Kernel 3: exact jax.lax.top_k(516) order via full bitonic sort of 4096
// 64-bit keys (sortable-float, ~index). Masked positions forced to +inf.
// ---------------------------------------------------------------------------
__global__ __launch_bounds__(1024) void k3_topk(
    const float* __restrict__ tk, int* __restrict__ indices) {
  int bh = blockIdx.x;
  __shared__ unsigned long long keys[4096];
  int t = threadIdx.x;
  for (int s = t; s < 4096; s += 1024) {
    unsigned u;
    if (s < SINKN || s >= SEQKV - LOCALK) {
      u = 0xFF800000u;  // sortable(+inf)
    } else {
      float v = tk[(bh << 12) + s];
      unsigned b = __float_as_uint(v);
      u = (b & 0x80000000u) ? ~b : (b | 0x80000000u);
    }
    keys[s] = ((unsigned long long)u << 32) | (unsigned)(~s);
  }
  __syncthreads();
  for (int k = 2; k <= 4096; k <<= 1) {
    for (int j = k >> 1; j > 0; j >>= 1) {
      for (int i = t; i < 4096; i += 1024) {
        int ixj = i ^ j;
        if (ixj > i) {
          bool desc = ((i & k) == 0);
          unsigned long long a = keys[i], bb = keys[ixj];
          if ((a < bb) == desc) { keys[i] = bb; keys[ixj] = a; }
        }
      }
      __syncthreads();
    }
  }
  for (int j = t; j < KSEL; j += 1024)
    indices[bh * KSEL + j] = (int)(~((unsigned)(keys[j] & 0xFFFFFFFFu)));
}

// ---------------------------------------------------------------------------
// Kernel 5: gathered QK^T scores. grid (32 bh, 13), block 256 = 4 waves.
// wave handles j = blockIdx.y*4 + wave + 52*i  (52 waves per bh).
// ---------------------------------------------------------------------------
__global__ __launch_bounds__(256) void k5_qk(
    const float* __restrict__ q, const float* __restrict__ key,
    const float* __restrict__ lm, const float* __restrict__ key_cpu,
    const int* __restrict__ indices, float* __restrict__ s2_g) {
  int bh = blockIdx.y;
  int t = threadIdx.x;
  int wave = t >> 6, lane = t & 63;
  __shared__ float qs[512];
  __shared__ int sidx[KSEL];
  qs[t] = q[((size_t)bh * 4 << 7) + t];
  qs[t + 256] = q[((size_t)bh * 4 << 7) + t + 256];
  for (int j = t; j < KSEL; j += 256) sidx[j] = indices[bh * KSEL + j];
  __syncthreads();

  const float rsqd = 0.08838834764831845f;  // 1/sqrt(128)
  float q0a = qs[lane * 2], q0b = qs[lane * 2 + 1];
  float q1a = qs[128 + lane * 2], q1b = qs[128 + lane * 2 + 1];
  float q2a = qs[256 + lane * 2], q2b = qs[256 + lane * 2 + 1];
  float q3a = qs[384 + lane * 2], q3b = qs[384 + lane * 2 + 1];

  for (int i = 0; i < 10; ++i) {
    int j = (blockIdx.x << 2) + wave + 52 * i;
    if (j > KSEL) continue;
    int sj = (j < KSEL) ? sidx[j] : SEQKV;
    const float* krow = (j < KSEL)
        ? key_cpu + ((((size_t)bh << 12) + sj) << 7)
        : key + ((size_t)bh << 7);
    float2 kk = ((const float2*)krow)[lane];
    float p0 = q0a * kk.x + q0b * kk.y;
    float p1 = q1a * kk.x + q1b * kk.y;
    float p2 = q2a * kk.x + q2b * kk.y;
    float p3 = q3a * kk.x + q3b * kk.y;
    for (int off = 32; off > 0; off >>= 1) {
      p0 += __shfl_down(p0, off);
      p1 += __shfl_down(p1, off);
      p2 += __shfl_down(p2, off);
      p3 += __shfl_down(p3, off);
    }
    if (lane == 0) {
      size_t lmb = (size_t)bh * 4 * SEQN + sj;
      s2_g[(bh * 4 + 0) * 520 + j] = p0 * rsqd + lm[lmb + 0 * SEQN];
      s2_g[(bh * 4 + 1) * 520 + j] = p1 * rsqd + lm[lmb + 1 * SEQN];
      s2_g[(bh * 4 + 2) * 520 + j] = p2 * rsqd + lm[lmb + 2 * SEQN];
      s2_g[(bh * 4 + 3) * 520 + j] = p3 * rsqd + lm[lmb + 3 * SEQN];
    }
  }
}

// ---------------------------------------------------------------------------
// Kernel 6: per (bh,p): full-softmax stats -> kv_weight; softmax over the
// 517 gathered scores; writes out_w, w_g, and initializes out with the
// (1-kvw)*mean_v_new term. grid 128, block 256.
// ---------------------------------------------------------------------------
__global__ __launch_bounds__(256) void k6_stats(
    const float* __restrict__ scores, const int* __restrict__ indices,
    const float* __restrict__ s2_g, const float* __restrict__ value,
    const float* __restrict__ mean_v,
    float* __restrict__ out_w, float* __restrict__ w_g,
    float* __restrict__ out) {
  int bhp = blockIdx.x;
  int bh = bhp >> 2;
  int t = threadIdx.x;
  __shared__ int sidx[KSEL];
  __shared__ float red[256];
  __shared__ float bc;

  for (int j = t; j < KSEL; j += 256) sidx[j] = indices[bh * KSEL + j];
  __syncthreads();

  const float* srow = scores + (size_t)bhp * SEQN;
  // max over 4097
  float mx = -INFINITY;
  for (int s = t; s < SEQN; s += 256) mx = fmaxf(mx, srow[s]);
  red[t] = mx; __syncthreads();
  for (int st = 128; st > 0; st >>= 1) {
    if (t < st) red[t] = fmaxf(red[t], red[t + st]);
    __syncthreads();
  }
  float m = red[0]; __syncthreads();
  // total sum of exp
  float se = 0.f;
  for (int s = t; s < SEQN; s += 256) se += expf(srow[s] - m);
  red[t] = se; __syncthreads();
  for (int st = 128; st > 0; st >>= 1) {
    if (t < st) red[t] += red[t + st];
    __syncthreads();
  }
  float sumexp = red[0]; __syncthreads();
  // selected mass
  float ss = 0.f;
  for (int j = t; j < KSEL; j += 256) ss += expf(srow[sidx[j]] - m);
  red[t] = ss; __syncthreads();
  for (int st = 128; st > 0; st >>= 1) {
    if (t < st) red[t] += red[t + st];
    __syncthreads();
  }
  float kvw;
  if (t == 0) bc = (red[0] + expf(srow[SEQKV] - m)) / sumexp;
  __syncthreads();
  kvw = bc; __syncthreads();

  // softmax over 517 gathered scores
  const float* s2r = s2_g + (size_t)bhp * 520;
  float mx2 = -INFINITY;
  for (int j = t; j < KSEL + 1; j += 256) mx2 = fmaxf(mx2, s2r[j]);
  red[t] = mx2; __syncthreads();
  for (int st = 128; st > 0; st >>= 1) {
    if (t < st) red[t] = fmaxf(red[t], red[t + st]);
    __syncthreads();
  }
  float m2 = red[0]; __syncthreads();
  float se2 = 0.f;
  for (int j = t; j < KSEL + 1; j += 256) se2 += expf(s2r[j] - m2);
  red[t] = se2; __syncthreads();
  for (int st = 128; st > 0; st >>= 1) {
    if (t < st) red[t] += red[t + st];
    __syncthreads();
  }
  float inv = kvw / red[0];

  for (int j = t; j < KSEL + 1; j += 256) {
    float w = expf(s2r[j] - m2) * inv;
    out_w[(size_t)bhp * (KSEL + 1) + j] = w;
    w_g[(size_t)bhp * 520 + j] = w;
  }

  // initialize out with (1-kvw) * mean_v_new
  if (t < 128) {
    float vcur = value[((size_t)bh << 7) + t];
    float mvn = (mean_v[((size_t)bh << 7) + t] * 4096.f + vcur) / 4097.f;
    out[((size_t)bhp << 7) + t] = (1.f - kvw) * mvn;
  }
}

// ---------------------------------------------------------------------------
// Kernel 7: out += sum_j w[p][j] * V_g[j][:]. grid (32 bh, 9 chunks of 64 j),
// block 256 (2 j-lanes x 128 d). atomicAdd accumulation into out.
// ---------------------------------------------------------------------------
__global__ __launch_bounds__(256) void k7_wv(
    const float* __restrict__ value, const float* __restrict__ value_cpu,
    const int* __restrict__ indices, const float* __restrict__ w_g,
    float* __restrict__ out) {
  int bh = blockIdx.y;
  int c0 = blockIdx.x << 6;  // chunk start j
  int t = threadIdx.x;
  int d = t & 127, half = t >> 7;
  __shared__ int sidx[64];
  __shared__ float wsh[4][64];
  __shared__ float red[2][4][128];

  int nj = min(64, KSEL + 1 - c0);
  if (t < nj) {
    int j = c0 + t;
    sidx[t] = (j < KSEL) ? indices[bh * KSEL + j] : -1;
  }
  for (int i = t; i < 4 * 64; i += 256) {
    int p = i >> 6, jl = i & 63;
    wsh[p][jl] = (jl < nj) ? w_g[(size_t)(bh * 4 + p) * 520 + c0 + jl] : 0.f;
  }
  __syncthreads();

  float a0 = 0, a1 = 0, a2 = 0, a3 = 0;
  for (int jl = half; jl < nj; jl += 2) {
    int sj = sidx[jl];
    const float* vrow = (sj >= 0)
        ? value_cpu + ((((size_t)bh << 12) + sj) << 7)
        : value + ((size_t)bh << 7);
    float v = vrow[d];
    a0 += wsh[0][jl] * v;
    a1 += wsh[1][jl] * v;
    a2 += wsh[2][jl] * v;
    a3 += wsh[3][jl] * v;
  }
  red[half][0][d] = a0; red[half][1][d] = a1;
  red[half][2][d] = a2; red[half][3][d] = a3;
  __syncthreads();
  if (half == 0) {
#pragma unroll
    for (int p = 0; p < 4; ++p) {
      float s = red[0][p][d] + red[1][p][d];
      atomicAdd(&out[(size_t)(bh * 4 + p) * 128 + d], s);
    }
  }
}

// ---------------------------------------------------------------------------
extern "C" void kernel_launch(void* const* d_in, const int* in_sizes, int n_in,
                              void* d_out, int out_size, void* d_ws, size_t ws_size,
                              hipStream_t stream) {
  const float* query     = (const float*)d_in[0];
  const float* key       = (const float*)d_in[1];
  const float* value     = (const float*)d_in[2];
  const float* logmask   = (const float*)d_in[3];
  const float* key_cpu   = (const float*)d_in[4];
  const float* value_cpu = (const float*)d_in[5];
  const float* s_key_cpu = (const float*)d_in[6];
  const float* mean_v    = (const float*)d_in[7];

  float* out   = (float*)d_out;       // (4,32,1,128) = 16384 floats
  float* out_w = out + 16384;         // (4,32,1,517) = 66176 floats

  char* ws = (char*)d_ws;
  float* qp_scaled = (float*)ws;                  // 16384 B
  int*   sidx      = (int*)(ws + 16384);          // 4096 B
  int*   indices   = (int*)(ws + 20480);          // 66048 B
  float* scores    = (float*)(ws + 86528);        // 2097664 B
  float* tk        = (float*)(ws + 2184192);      // 524288 B
  float* s2_g      = (float*)(ws + 2708480);      // 32*4*520*4 = 266240 B
  float* w_g       = (float*)(ws + 2974720);      // 266240 B
  // total ws use: 3,240,960 bytes

  hipLaunchKernelGGL(k1_prep, dim3(NBH), dim3(128), 0, stream,
                     query, key, logmask, qp_scaled, sidx, scores);
  hipLaunchKernelGGL(k2_scores, dim3(8, NBH), dim3(256), 0, stream,
                     s_key_cpu, logmask, qp_scaled, sidx, scores, tk);
  hipLaunchKernelGGL(k3_topk, dim3(NBH), dim3(1024), 0, stream,
                     tk, indices);
  hipLaunchKernelGGL(k5_qk, dim3(13, NBH), dim3(256), 0, stream,
                     query, key, logmask, key_cpu, indices, s2_g);
  hipLaunchKernelGGL(k6_stats, dim3(128), dim3(256), 0, stream,
                     scores, indices, s2_g, value, mean_v, out_w, w_g, out);
  hipLaunchKernelGGL(k7_wv, dim3(9, NBH), dim3(256), 0, stream,
                     value, value_cpu, indices, w_g, out);
}

// Round 3
// 256.572 us; speedup vs baseline: 1.4275x; 1.1192x over previous
//
#include <hip/hip_runtime.h>
#include <hip/hip_bf16.h>
#include <math.h>

// Problem constants
#define NBH 32     // B*KVH = 4*8
#define HPKN 4
#define DN 128
#define SEQKV 4096
#define SEQN 4097
#define SSTR 4100  // padded score-row stride (keeps float4 alignment per row)
#define RANKN 32
#define KSEL 516   // K + SINK = 512 + 4
#define SINKN 4
#define LOCALK 128 // masked-local region starts at SEQKV - LOCALK = 3968
#define NMASK 132  // SINKN + LOCALK
#define NTOP 384   // KSEL - NMASK

// ---------------------------------------------------------------------------
// Kernel 1: per (b,h): top-32 dims of sum_p |q|, scale, pre-scaled q_proj,
// and the current-token (s=4096) approximate score.
// ---------------------------------------------------------------------------
__global__ __launch_bounds__(128) void k1_prep(
    const float* __restrict__ q, const float* __restrict__ key,
    const float* __restrict__ lm,
    float* __restrict__ qp_scaled, int* __restrict__ sidx_g,
    float* __restrict__ scores) {
  int bh = blockIdx.x;
  int b = bh >> 3, h = bh & 7;
  int d = threadIdx.x;
  __shared__ float qv[4][128];
  __shared__ float absq[128];
  __shared__ int sel[RANKN];
  __shared__ float red[128];
  __shared__ float scale_s[4];

  float a = 0.f;
  for (int p = 0; p < 4; ++p) {
    float val = q[((b * 32 + h * 4 + p) << 7) + d];
    qv[p][d] = val;
    a += fabsf(val);
  }
  absq[d] = a;
  __syncthreads();

  // rank of my dim among 128 (desc value, asc index tiebreak)
  int rank = 0;
  for (int e = 0; e < 128; ++e) {
    float ae = absq[e];
    rank += (ae > a) || (ae == a && e < d);
  }
  if (rank < RANKN) sel[rank] = d;
  __syncthreads();

  for (int p = 0; p < 4; ++p) {
    red[d] = fabsf(qv[p][d]);
    __syncthreads();
    for (int s = 64; s > 0; s >>= 1) { if (d < s) red[d] += red[d + s]; __syncthreads(); }
    float full = red[0];
    __syncthreads();
    red[d] = (d < RANKN) ? fabsf(qv[p][sel[d]]) : 0.f;
    __syncthreads();
    for (int s = 64; s > 0; s >>= 1) { if (d < s) red[d] += red[d + s]; __syncthreads(); }
    if (d == 0) scale_s[p] = sqrtf(red[0] / full * 128.f);
    __syncthreads();
    if (d < RANKN) qp_scaled[(bh * 4 + p) * RANKN + d] = qv[p][sel[d]] / scale_s[p];
    __syncthreads();
  }
  if (d < RANKN) sidx_g[bh * RANKN + d] = sel[d];

  // approximate score at s = 4096 (current key)
  float keyv = (d < RANKN) ? key[bh * 128 + sel[d]] : 0.f;
  for (int p = 0; p < 4; ++p) {
    red[d] = (d < RANKN) ? (qv[p][sel[d]] / scale_s[p]) * keyv : 0.f;
    __syncthreads();
    for (int s = 64; s > 0; s >>= 1) { if (d < s) red[d] += red[d + s]; __syncthreads(); }
    if (d == 0)
      scores[(size_t)(bh * 4 + p) * SSTR + SEQKV] =
          red[0] + lm[(size_t)(b * 32 + h * 4 + p) * SEQN + SEQKV];
    __syncthreads();
  }
}

// ---------------------------------------------------------------------------
// Kernel 2: approximate scores over history, and per-position sum over p.
// grid (8 chunks of 512 positions, 32 bh), block 256.
// ---------------------------------------------------------------------------
__global__ __launch_bounds__(256) void k2_scores(
    const float* __restrict__ skey, const float* __restrict__ lm,
    const float* __restrict__ qp_scaled, const int* __restrict__ sidx_g,
    float* __restrict__ scores, float* __restrict__ tk) {
  int bh = blockIdx.y;
  int b = bh >> 3, h = bh & 7;
  int s0 = blockIdx.x << 9;
  int t = threadIdx.x;
  __shared__ float qp[4][RANKN];
  __shared__ int sel[RANKN];
  if (t < 128) qp[t >> 5][t & 31] = qp_scaled[bh * 128 + t];
  if (t < RANKN) sel[t] = sidx_g[bh * RANKN + t];
  __syncthreads();
  const float* kb = skey + (size_t)bh * 128 * 4096;
  float a00 = 0, a01 = 0, a02 = 0, a03 = 0;
  float a10 = 0, a11 = 0, a12 = 0, a13 = 0;
#pragma unroll 4
  for (int r = 0; r < RANKN; ++r) {
    const float* row = kb + ((size_t)sel[r] << 12) + s0;
    float k0 = row[t];
    float k1 = row[t + 256];
    float q0 = qp[0][r], q1 = qp[1][r], q2 = qp[2][r], q3 = qp[3][r];
    a00 += q0 * k0; a01 += q1 * k0; a02 += q2 * k0; a03 += q3 * k0;
    a10 += q0 * k1; a11 += q1 * k1; a12 += q2 * k1; a13 += q3 * k1;
  }
  float acc0[4] = {a00, a01, a02, a03};
  float acc1[4] = {a10, a11, a12, a13};
  {
    int s = s0 + t;
    float sum = 0;
    for (int p = 0; p < 4; ++p) {
      float sc = acc0[p] + lm[(size_t)(b * 32 + h * 4 + p) * SEQN + s];
      scores[(size_t)(bh * 4 + p) * SSTR + s] = sc;
      sum += sc;
    }
    tk[(bh << 12) + s] = sum;
  }
  {
    int s = s0 + t + 256;
    float sum = 0;
    for (int p = 0; p < 4; ++p) {
      float sc = acc1[p] + lm[(size_t)(b * 32 + h * 4 + p) * SEQN + s];
      scores[(size_t)(bh * 4 + p) * SSTR + s] = sc;
      sum += sc;
    }
    tk[(bh << 12) + s] = sum;
  }
}

// ---------------------------------------------------------------------------
// Kernel 3: top-384-of-3964 radix-select + small bitonic sorts. Exact
// jax.lax.top_k(516) order: 132 masked (+inf) indices first (ascending),
// then the top-384 real sums descending, ties -> lower index.
// ---------------------------------------------------------------------------
__global__ __launch_bounds__(256) void k3_topk(
    const float* __restrict__ tk, int* __restrict__ indices) {
  int bh = blockIdx.x;
  int t = threadIdx.x;
  __shared__ unsigned us[4096];               // sortable keys, 16 KB
  __shared__ unsigned hist[2048];             // 8 KB
  __shared__ unsigned long long binlist[2048];// 16 KB
  __shared__ unsigned long long selk[512];    // 4 KB
  __shared__ unsigned chunkSum[32];
  __shared__ int c1, c2, binB_s, nAbove_s, needed_s;

  for (int s = t; s < 4096; s += 256) {
    unsigned b = __float_as_uint(tk[(bh << 12) + s]);
    us[s] = (b & 0x80000000u) ? ~b : (b | 0x80000000u);
  }
  for (int i = t; i < 2048; i += 256) hist[i] = 0;
  if (t == 0) { c1 = 0; c2 = 0; }
  __syncthreads();

  // histogram of candidates s in [SINKN, SEQKV-LOCALK) on top 11 bits
  for (int s = SINKN + t; s < SEQKV - LOCALK; s += 256)
    atomicAdd(&hist[us[s] >> 21], 1u);
  __syncthreads();

  if (t < 32) {
    unsigned sum = 0;
    for (int i = 0; i < 64; ++i) sum += hist[t * 64 + i];
    chunkSum[t] = sum;
  }
  __syncthreads();

  if (t < 64) {
    int lane = t;
    // suffix-inclusive sum over 32 chunk sums (higher chunk = larger keys)
    unsigned x = (lane < 32) ? chunkSum[lane] : 0;
    unsigned sfx = x;
    for (int off = 1; off < 64; off <<= 1) {
      unsigned y = __shfl_down(sfx, off);
      if (lane + off < 64) sfx += y;
    }
    unsigned above = sfx - x;  // count in chunks strictly above mine
    bool hit = (lane < 32) && (above < NTOP) && (above + x >= NTOP);
    unsigned long long mask = __ballot(hit);
    int C = __ffsll(mask) - 1;
    unsigned aboveC = __shfl(above, C);
    // refine within chunk C over its 64 bins
    unsigned h = hist[C * 64 + lane];
    unsigned sfx2 = h;
    for (int off = 1; off < 64; off <<= 1) {
      unsigned y = __shfl_down(sfx2, off);
      if (lane + off < 64) sfx2 += y;
    }
    unsigned above2 = aboveC + (sfx2 - h);
    bool hit2 = (above2 < NTOP) && (above2 + h >= NTOP);
    unsigned long long mask2 = __ballot(hit2);
    int lB = __ffsll(mask2) - 1;
    if (lane == lB) {
      binB_s = C * 64 + lane;
      nAbove_s = (int)above2;
      needed_s = NTOP - (int)above2;
    }
  }
  __syncthreads();
  unsigned B = (unsigned)binB_s;
  int nAbove = nAbove_s, needed = needed_s;

  // collect: definite winners -> selk, boundary-bin members -> binlist
  for (int s = SINKN + t; s < SEQKV - LOCALK; s += 256) {
    unsigned u = us[s];
    unsigned bin = u >> 21;
    unsigned long long key = ((unsigned long long)u << 32) | (unsigned)(~s);
    if (bin > B) {
      selk[atomicAdd(&c1, 1)] = key;
    } else if (bin == B) {
      int pos = atomicAdd(&c2, 1);
      if (pos < 2048) binlist[pos] = key;
    }
  }
  __syncthreads();
  int m2 = c2;
  int p2 = 1;
  while (p2 < m2) p2 <<= 1;
  for (int i = m2 + t; i < p2; i += 256) binlist[i] = 0ULL;
  __syncthreads();
  // bitonic sort (descending) of the boundary bin
  for (int k = 2; k <= p2; k <<= 1)
    for (int j = k >> 1; j > 0; j >>= 1) {
      for (int i = t; i < p2; i += 256) {
        int ixj = i ^ j;
        if (ixj > i) {
          bool desc = ((i & k) == 0);
          unsigned long long a = binlist[i], bb = binlist[ixj];
          if ((a < bb) == desc) { binlist[i] = bb; binlist[ixj] = a; }
        }
      }
      __syncthreads();
    }
  for (int i = t; i < needed; i += 256) selk[nAbove + i] = binlist[i];
  for (int i = NTOP + t; i < 512; i += 256) selk[i] = 0ULL;
  __syncthreads();
  // bitonic sort (descending) of 512
  for (int k = 2; k <= 512; k <<= 1)
    for (int j = k >> 1; j > 0; j >>= 1) {
      for (int i = t; i < 512; i += 256) {
        int ixj = i ^ j;
        if (ixj > i) {
          bool desc = ((i & k) == 0);
          unsigned long long a = selk[i], bb = selk[ixj];
          if ((a < bb) == desc) { selk[i] = bb; selk[ixj] = a; }
        }
      }
      __syncthreads();
    }
  // emit: masked first (index-ascending), then top-384 descending
  if (t < SINKN) indices[bh * KSEL + t] = t;
  for (int i = t; i < LOCALK; i += 256)
    indices[bh * KSEL + SINKN + i] = (SEQKV - LOCALK) + i;
  for (int i = t; i < NTOP; i += 256)
    indices[bh * KSEL + NMASK + i] = (int)(~(unsigned)(selk[i] & 0xFFFFFFFFu));
}

// ---------------------------------------------------------------------------
// Kernel 5: gathered QK^T scores. grid (13, 32 bh), block 256 = 4 waves.
// ---------------------------------------------------------------------------
__global__ __launch_bounds__(256) void k5_qk(
    const float* __restrict__ q, const float* __restrict__ key,
    const float* __restrict__ lm, const float* __restrict__ key_cpu,
    const int* __restrict__ indices, float* __restrict__ s2_g) {
  int bh = blockIdx.y;
  int t = threadIdx.x;
  int wave = t >> 6, lane = t & 63;
  __shared__ float qs[512];
  __shared__ int sidx[KSEL];
  qs[t] = q[((size_t)bh * 4 << 7) + t];
  qs[t + 256] = q[((size_t)bh * 4 << 7) + t + 256];
  for (int j = t; j < KSEL; j += 256) sidx[j] = indices[bh * KSEL + j];
  __syncthreads();

  const float rsqd = 0.08838834764831845f;  // 1/sqrt(128)
  float q0a = qs[lane * 2], q0b = qs[lane * 2 + 1];
  float q1a = qs[128 + lane * 2], q1b = qs[128 + lane * 2 + 1];
  float q2a = qs[256 + lane * 2], q2b = qs[256 + lane * 2 + 1];
  float q3a = qs[384 + lane * 2], q3b = qs[384 + lane * 2 + 1];

  for (int i = 0; i < 10; ++i) {
    int j = (blockIdx.x << 2) + wave + 52 * i;
    if (j > KSEL) continue;
    int sj = (j < KSEL) ? sidx[j] : SEQKV;
    const float* krow = (j < KSEL)
        ? key_cpu + ((((size_t)bh << 12) + sj) << 7)
        : key + ((size_t)bh << 7);
    float2 kk = ((const float2*)krow)[lane];
    float p0 = q0a * kk.x + q0b * kk.y;
    float p1 = q1a * kk.x + q1b * kk.y;
    float p2 = q2a * kk.x + q2b * kk.y;
    float p3 = q3a * kk.x + q3b * kk.y;
    for (int off = 32; off > 0; off >>= 1) {
      p0 += __shfl_down(p0, off);
      p1 += __shfl_down(p1, off);
      p2 += __shfl_down(p2, off);
      p3 += __shfl_down(p3, off);
    }
    if (lane == 0) {
      size_t lmb = (size_t)bh * 4 * SEQN + sj;
      s2_g[(bh * 4 + 0) * 520 + j] = p0 * rsqd + lm[lmb + 0 * SEQN];
      s2_g[(bh * 4 + 1) * 520 + j] = p1 * rsqd + lm[lmb + 1 * SEQN];
      s2_g[(bh * 4 + 2) * 520 + j] = p2 * rsqd + lm[lmb + 2 * SEQN];
      s2_g[(bh * 4 + 3) * 520 + j] = p3 * rsqd + lm[lmb + 3 * SEQN];
    }
  }
}

// ---------------------------------------------------------------------------
// Kernel 6: per (bh,p): full-softmax stats -> kv_weight; softmax over the
// 517 gathered scores; writes out_w, w_g, and initializes out with the
// (1-kvw)*mean_v_new term. grid 128, block 256.
// ---------------------------------------------------------------------------
__global__ __launch_bounds__(256) void k6_stats(
    const float* __restrict__ scores, const int* __restrict__ indices,
    const float* __restrict__ s2_g, const float* __restrict__ value,
    const float* __restrict__ mean_v,
    float* __restrict__ out_w, float* __restrict__ w_g,
    float* __restrict__ out) {
  int bhp = blockIdx.x;
  int bh = bhp >> 2;
  int t = threadIdx.x;
  __shared__ int sidx[KSEL];
  __shared__ float red[256];
  __shared__ float bc;

  for (int j = t; j < KSEL; j += 256) sidx[j] = indices[bh * KSEL + j];
  __syncthreads();

  const float* srow = scores + (size_t)bhp * SSTR;
  const float4* srow4 = (const float4*)srow;
  // max over 4097 (vectorized over the first 4096)
  float mx = -INFINITY;
  for (int i = t; i < 1024; i += 256) {
    float4 v = srow4[i];
    mx = fmaxf(mx, fmaxf(fmaxf(v.x, v.y), fmaxf(v.z, v.w)));
  }
  if (t == 0) mx = fmaxf(mx, srow[SEQKV]);
  red[t] = mx; __syncthreads();
  for (int st = 128; st > 0; st >>= 1) {
    if (t < st) red[t] = fmaxf(red[t], red[t + st]);
    __syncthreads();
  }
  float m = red[0]; __syncthreads();
  // total sum of exp
  float se = 0.f;
  for (int i = t; i < 1024; i += 256) {
    float4 v = srow4[i];
    se += expf(v.x - m) + expf(v.y - m) + expf(v.z - m) + expf(v.w - m);
  }
  if (t == 0) se += expf(srow[SEQKV] - m);
  red[t] = se; __syncthreads();
  for (int st = 128; st > 0; st >>= 1) {
    if (t < st) red[t] += red[t + st];
    __syncthreads();
  }
  float sumexp = red[0]; __syncthreads();
  // selected mass
  float ss = 0.f;
  for (int j = t; j < KSEL; j += 256) ss += expf(srow[sidx[j]] - m);
  red[t] = ss; __syncthreads();
  for (int st = 128; st > 0; st >>= 1) {
    if (t < st) red[t] += red[t + st];
    __syncthreads();
  }
  float kvw;
  if (t == 0) bc = (red[0] + expf(srow[SEQKV] - m)) / sumexp;
  __syncthreads();
  kvw = bc; __syncthreads();

  // softmax over 517 gathered scores
  const float* s2r = s2_g + (size_t)bhp * 520;
  float mx2 = -INFINITY;
  for (int j = t; j < KSEL + 1; j += 256) mx2 = fmaxf(mx2, s2r[j]);
  red[t] = mx2; __syncthreads();
  for (int st = 128; st > 0; st >>= 1) {
    if (t < st) red[t] = fmaxf(red[t], red[t + st]);
    __syncthreads();
  }
  float m2 = red[0]; __syncthreads();
  float se2 = 0.f;
  for (int j = t; j < KSEL + 1; j += 256) se2 += expf(s2r[j] - m2);
  red[t] = se2; __syncthreads();
  for (int st = 128; st > 0; st >>= 1) {
    if (t < st) red[t] += red[t + st];
    __syncthreads();
  }
  float inv = kvw / red[0];

  for (int j = t; j < KSEL + 1; j += 256) {
    float w = expf(s2r[j] - m2) * inv;
    out_w[(size_t)bhp * (KSEL + 1) + j] = w;
    w_g[(size_t)bhp * 520 + j] = w;
  }

  // initialize out with (1-kvw) * mean_v_new
  if (t < 128) {
    float vcur = value[((size_t)bh << 7) + t];
    float mvn = (mean_v[((size_t)bh << 7) + t] * 4096.f + vcur) / 4097.f;
    out[((size_t)bhp << 7) + t] = (1.f - kvw) * mvn;
  }
}

// ---------------------------------------------------------------------------
// Kernel 7: out += sum_j w[p][j] * V_g[j][:]. grid (9, 32 bh), block 256.
// ---------------------------------------------------------------------------
__global__ __launch_bounds__(256) void k7_wv(
    const float* __restrict__ value, const float* __restrict__ value_cpu,
    const int* __restrict__ indices, const float* __restrict__ w_g,
    float* __restrict__ out) {
  int bh = blockIdx.y;
  int c0 = blockIdx.x << 6;  // chunk start j
  int t = threadIdx.x;
  int d = t & 127, half = t >> 7;
  __shared__ int sidx[64];
  __shared__ float wsh[4][64];
  __shared__ float red[2][4][128];

  int nj = min(64, KSEL + 1 - c0);
  if (t < nj) {
    int j = c0 + t;
    sidx[t] = (j < KSEL) ? indices[bh * KSEL + j] : -1;
  }
  for (int i = t; i < 4 * 64; i += 256) {
    int p = i >> 6, jl = i & 63;
    wsh[p][jl] = (jl < nj) ? w_g[(size_t)(bh * 4 + p) * 520 + c0 + jl] : 0.f;
  }
  __syncthreads();

  float a0 = 0, a1 = 0, a2 = 0, a3 = 0;
  for (int jl = half; jl < nj; jl += 2) {
    int sj = sidx[jl];
    const float* vrow = (sj >= 0)
        ? value_cpu + ((((size_t)bh << 12) + sj) << 7)
        : value + ((size_t)bh << 7);
    float v = vrow[d];
    a0 += wsh[0][jl] * v;
    a1 += wsh[1][jl] * v;
    a2 += wsh[2][jl] * v;
    a3 += wsh[3][jl] * v;
  }
  red[half][0][d] = a0; red[half][1][d] = a1;
  red[half][2][d] = a2; red[half][3][d] = a3;
  __syncthreads();
  if (half == 0) {
#pragma unroll
    for (int p = 0; p < 4; ++p) {
      float s = red[0][p][d] + red[1][p][d];
      atomicAdd(&out[(size_t)(bh * 4 + p) * 128 + d], s);
    }
  }
}

// ---------------------------------------------------------------------------
extern "C" void kernel_launch(void* const* d_in, const int* in_sizes, int n_in,
                              void* d_out, int out_size, void* d_ws, size_t ws_size,
                              hipStream_t stream) {
  const float* query     = (const float*)d_in[0];
  const float* key       = (const float*)d_in[1];
  const float* value     = (const float*)d_in[2];
  const float* logmask   = (const float*)d_in[3];
  const float* key_cpu   = (const float*)d_in[4];
  const float* value_cpu = (const float*)d_in[5];
  const float* s_key_cpu = (const float*)d_in[6];
  const float* mean_v    = (const float*)d_in[7];

  float* out   = (float*)d_out;       // (4,32,1,128) = 16384 floats
  float* out_w = out + 16384;         // (4,32,1,517) = 66176 floats

  char* ws = (char*)d_ws;
  float* qp_scaled = (float*)ws;                  // 16384 B
  int*   sidx      = (int*)(ws + 16384);          // 4096 B
  int*   indices   = (int*)(ws + 20480);          // 66048 B
  float* scores    = (float*)(ws + 86528);        // 128*4100*4 = 2099200 B
  float* tk        = (float*)(ws + 2185728);      // 524288 B
  float* s2_g      = (float*)(ws + 2710016);      // 266240 B
  float* w_g       = (float*)(ws + 2976256);      // 266240 B
  // total ws use: 3,242,496 bytes

  hipLaunchKernelGGL(k1_prep, dim3(NBH), dim3(128), 0, stream,
                     query, key, logmask, qp_scaled, sidx, scores);
  hipLaunchKernelGGL(k2_scores, dim3(8, NBH), dim3(256), 0, stream,
                     s_key_cpu, logmask, qp_scaled, sidx, scores, tk);
  hipLaunchKernelGGL(k3_topk, dim3(NBH), dim3(256), 0, stream,
                     tk, indices);
  hipLaunchKernelGGL(k5_qk, dim3(13, NBH), dim3(256), 0, stream,
                     query, key, logmask, key_cpu, indices, s2_g);
  hipLaunchKernelGGL(k6_stats, dim3(128), dim3(256), 0, stream,
                     scores, indices, s2_g, value, mean_v, out_w, w_g, out);
  hipLaunchKernelGGL(k7_wv, dim3(9, NBH), dim3(256), 0, stream,
                     value, value_cpu, indices, w_g, out);
}

// Round 4
// 248.492 us; speedup vs baseline: 1.4739x; 1.0325x over previous
//
#include <hip/hip_runtime.h>
#include <hip/hip_bf16.h>
#include <math.h>

// Problem constants
#define NBH 32     // B*KVH = 4*8
#define HPKN 4
#define DN 128
#define SEQKV 4096
#define SEQN 4097
#define SSTR 4100  // padded score-row stride (keeps float4 alignment per row)
#define RANKN 32
#define KSEL 516   // K + SINK = 512 + 4
#define SINKN 4
#define LOCALK 128 // masked-local region starts at SEQKV - LOCALK = 3968
#define NMASK 132  // SINKN + LOCALK
#define NTOP 384   // KSEL - NMASK

// ---------------------------------------------------------------------------
// Kernel 2 (fused with old k1): per block, recompute rank-32 dim selection +
// scales from q via shuffle reductions (cheap, 4 barriers), then approximate
// scores over this block's 512-position chunk. Block x==0 also writes the
// current-token (s=4096) score. grid (8, 32 bh), block 256.
// ---------------------------------------------------------------------------
__global__ __launch_bounds__(256) void k2_scores(
    const float* __restrict__ q, const float* __restrict__ key,
    const float* __restrict__ skey, const float* __restrict__ lm,
    float* __restrict__ scores, float* __restrict__ tk) {
  int bh = blockIdx.y;
  int s0 = blockIdx.x << 9;
  int t = threadIdx.x;
  int wave = t >> 6, lane = t & 63;
  __shared__ float qv[4][128];
  __shared__ float absq[128];
  __shared__ int sel[RANKN];
  __shared__ float qp[4][RANKN];

  // ---- selection prep (replicated per block; ~4 barriers) ----
  {
    float v0 = q[(size_t)bh * 512 + t];
    float v1 = q[(size_t)bh * 512 + 256 + t];
    qv[t >> 7][t & 127] = v0;
    qv[2 + (t >> 7)][t & 127] = v1;
  }
  __syncthreads();
  if (t < 128)
    absq[t] = fabsf(qv[0][t]) + fabsf(qv[1][t]) + fabsf(qv[2][t]) + fabsf(qv[3][t]);
  __syncthreads();
  if (t < 128) {
    float a = absq[t];
    int rank = 0;
    for (int e = 0; e < 128; ++e) {
      float ae = absq[e];
      rank += (ae > a) || (ae == a && e < t);
    }
    if (rank < RANKN) sel[rank] = t;
  }
  __syncthreads();
  // per-p (wave==p) full |q| sum and selected |q| sum via shuffles
  {
    float fa = fabsf(qv[wave][lane]) + fabsf(qv[wave][lane + 64]);
    for (int off = 32; off > 0; off >>= 1) fa += __shfl_down(fa, off);
    float full = __shfl(fa, 0);
    float qsel = (lane < RANKN) ? qv[wave][sel[lane]] : 0.f;
    float sv = fabsf(qsel);
    for (int off = 32; off > 0; off >>= 1) sv += __shfl_down(sv, off);
    float selsum = __shfl(sv, 0);
    float scale = sqrtf(selsum / full * 128.f);
    if (lane < RANKN) qp[wave][lane] = qsel / scale;
  }
  __syncthreads();

  // current-token score (block x==0 only; wave == p)
  if (blockIdx.x == 0) {
    float kv = (lane < RANKN) ? key[bh * 128 + sel[lane]] : 0.f;
    float pr = (lane < RANKN) ? qp[wave][lane] * kv : 0.f;
    for (int off = 32; off > 0; off >>= 1) pr += __shfl_down(pr, off);
    if (lane == 0)
      scores[(size_t)(bh * 4 + wave) * SSTR + SEQKV] =
          pr + lm[(size_t)(bh * 4 + wave) * SEQN + SEQKV];
  }

  // ---- main approximate-score loop over this chunk ----
  const float* kb = skey + (size_t)bh * 128 * 4096;
  float a00 = 0, a01 = 0, a02 = 0, a03 = 0;
  float a10 = 0, a11 = 0, a12 = 0, a13 = 0;
#pragma unroll 4
  for (int r = 0; r < RANKN; ++r) {
    const float* row = kb + ((size_t)sel[r] << 12) + s0;
    float k0 = row[t];
    float k1 = row[t + 256];
    float q0 = qp[0][r], q1 = qp[1][r], q2 = qp[2][r], q3 = qp[3][r];
    a00 += q0 * k0; a01 += q1 * k0; a02 += q2 * k0; a03 += q3 * k0;
    a10 += q0 * k1; a11 += q1 * k1; a12 += q2 * k1; a13 += q3 * k1;
  }
  float acc0[4] = {a00, a01, a02, a03};
  float acc1[4] = {a10, a11, a12, a13};
  {
    int s = s0 + t;
    float sum = 0;
    for (int p = 0; p < 4; ++p) {
      float sc = acc0[p] + lm[(size_t)(bh * 4 + p) * SEQN + s];
      scores[(size_t)(bh * 4 + p) * SSTR + s] = sc;
      sum += sc;
    }
    tk[(bh << 12) + s] = sum;
  }
  {
    int s = s0 + t + 256;
    float sum = 0;
    for (int p = 0; p < 4; ++p) {
      float sc = acc1[p] + lm[(size_t)(bh * 4 + p) * SEQN + s];
      scores[(size_t)(bh * 4 + p) * SSTR + s] = sc;
      sum += sc;
    }
    tk[(bh << 12) + s] = sum;
  }
}

// ---------------------------------------------------------------------------
// Kernel 3: top-384-of-3964 radix-select + small bitonic sorts. Exact
// jax.lax.top_k(516) order: 132 masked (+inf) indices first (ascending),
// then the top-384 real sums descending, ties -> lower index.
// Compaction uses wave-aggregated ballots (1 LDS atomic per wave per cat).
// ---------------------------------------------------------------------------
__global__ __launch_bounds__(256) void k3_topk(
    const float* __restrict__ tk, int* __restrict__ indices) {
  int bh = blockIdx.x;
  int t = threadIdx.x;
  int lane = t & 63;
  __shared__ unsigned us[4096];               // sortable keys, 16 KB
  __shared__ unsigned hist[2048];             // 8 KB
  __shared__ unsigned long long binlist[2048];// 16 KB
  __shared__ unsigned long long selk[512];    // 4 KB
  __shared__ unsigned chunkSum[32];
  __shared__ int c1, c2, binB_s, nAbove_s, needed_s;

  for (int s = t; s < 4096; s += 256) {
    unsigned b = __float_as_uint(tk[(bh << 12) + s]);
    us[s] = (b & 0x80000000u) ? ~b : (b | 0x80000000u);
  }
  for (int i = t; i < 2048; i += 256) hist[i] = 0;
  if (t == 0) { c1 = 0; c2 = 0; }
  __syncthreads();

  // histogram of candidates s in [SINKN, SEQKV-LOCALK) on top 11 bits
  for (int s = SINKN + t; s < SEQKV - LOCALK; s += 256)
    atomicAdd(&hist[us[s] >> 21], 1u);
  __syncthreads();

  if (t < 32) {
    unsigned sum = 0;
    for (int i = 0; i < 64; ++i) sum += hist[t * 64 + i];
    chunkSum[t] = sum;
  }
  __syncthreads();

  if (t < 64) {
    int l = t;
    // suffix-inclusive sum over 32 chunk sums (higher chunk = larger keys)
    unsigned x = (l < 32) ? chunkSum[l] : 0;
    unsigned sfx = x;
    for (int off = 1; off < 64; off <<= 1) {
      unsigned y = __shfl_down(sfx, off);
      if (l + off < 64) sfx += y;
    }
    unsigned above = sfx - x;  // count in chunks strictly above mine
    bool hit = (l < 32) && (above < NTOP) && (above + x >= NTOP);
    unsigned long long mask = __ballot(hit);
    int C = __ffsll(mask) - 1;
    unsigned aboveC = __shfl(above, C);
    // refine within chunk C over its 64 bins
    unsigned h = hist[C * 64 + l];
    unsigned sfx2 = h;
    for (int off = 1; off < 64; off <<= 1) {
      unsigned y = __shfl_down(sfx2, off);
      if (l + off < 64) sfx2 += y;
    }
    unsigned above2 = aboveC + (sfx2 - h);
    bool hit2 = (above2 < NTOP) && (above2 + h >= NTOP);
    unsigned long long mask2 = __ballot(hit2);
    int lB = __ffsll(mask2) - 1;
    if (l == lB) {
      binB_s = C * 64 + l;
      nAbove_s = (int)above2;
      needed_s = NTOP - (int)above2;
    }
  }
  __syncthreads();
  unsigned B = (unsigned)binB_s;
  int nAbove = nAbove_s, needed = needed_s;

  // collect: definite winners -> selk, boundary-bin members -> binlist.
  // wave-aggregated compaction: one LDS atomic per wave per category.
  for (int s0 = SINKN; s0 < SEQKV - LOCALK; s0 += 256) {
    int s = s0 + t;
    bool valid = (s < SEQKV - LOCALK);
    unsigned u = valid ? us[s] : 0u;
    unsigned bin = u >> 21;
    bool win = valid && (bin > B);
    bool bnd = valid && (bin == B);
    unsigned long long mw = __ballot(win);
    unsigned long long mb = __ballot(bnd);
    int bw = 0, bb = 0;
    if (lane == 0) {
      if (mw) bw = atomicAdd(&c1, __popcll(mw));
      if (mb) bb = atomicAdd(&c2, __popcll(mb));
    }
    bw = __shfl(bw, 0);
    bb = __shfl(bb, 0);
    unsigned long long lmask = (1ULL << lane) - 1ULL;
    unsigned long long key = ((unsigned long long)u << 32) | (unsigned)(~s);
    if (win) selk[bw + __popcll(mw & lmask)] = key;
    if (bnd) {
      int pos = bb + __popcll(mb & lmask);
      if (pos < 2048) binlist[pos] = key;
    }
  }
  __syncthreads();
  int m2 = c2;
  int p2 = 1;
  while (p2 < m2) p2 <<= 1;
  for (int i = m2 + t; i < p2; i += 256) binlist[i] = 0ULL;
  __syncthreads();
  // bitonic sort (descending) of the boundary bin
  for (int k = 2; k <= p2; k <<= 1)
    for (int j = k >> 1; j > 0; j >>= 1) {
      for (int i = t; i < p2; i += 256) {
        int ixj = i ^ j;
        if (ixj > i) {
          bool desc = ((i & k) == 0);
          unsigned long long a = binlist[i], bb2 = binlist[ixj];
          if ((a < bb2) == desc) { binlist[i] = bb2; binlist[ixj] = a; }
        }
      }
      __syncthreads();
    }
  for (int i = t; i < needed; i += 256) selk[nAbove + i] = binlist[i];
  for (int i = NTOP + t; i < 512; i += 256) selk[i] = 0ULL;
  __syncthreads();
  // bitonic sort (descending) of 512
  for (int k = 2; k <= 512; k <<= 1)
    for (int j = k >> 1; j > 0; j >>= 1) {
      for (int i = t; i < 512; i += 256) {
        int ixj = i ^ j;
        if (ixj > i) {
          bool desc = ((i & k) == 0);
          unsigned long long a = selk[i], bb2 = selk[ixj];
          if ((a < bb2) == desc) { selk[i] = bb2; selk[ixj] = a; }
        }
      }
      __syncthreads();
    }
  // emit: masked first (index-ascending), then top-384 descending
  if (t < SINKN) indices[bh * KSEL + t] = t;
  for (int i = t; i < LOCALK; i += 256)
    indices[bh * KSEL + SINKN + i] = (SEQKV - LOCALK) + i;
  for (int i = t; i < NTOP; i += 256)
    indices[bh * KSEL + NMASK + i] = (int)(~(unsigned)(selk[i] & 0xFFFFFFFFu));
}

// ---------------------------------------------------------------------------
// Kernel 5: gathered QK^T scores. grid (13, 32 bh), block 256 = 4 waves.
// ---------------------------------------------------------------------------
__global__ __launch_bounds__(256) void k5_qk(
    const float* __restrict__ q, const float* __restrict__ key,
    const float* __restrict__ lm, const float* __restrict__ key_cpu,
    const int* __restrict__ indices, float* __restrict__ s2_g) {
  int bh = blockIdx.y;
  int t = threadIdx.x;
  int wave = t >> 6, lane = t & 63;
  __shared__ float qs[512];
  __shared__ int sidx[KSEL];
  qs[t] = q[((size_t)bh * 4 << 7) + t];
  qs[t + 256] = q[((size_t)bh * 4 << 7) + t + 256];
  for (int j = t; j < KSEL; j += 256) sidx[j] = indices[bh * KSEL + j];
  __syncthreads();

  const float rsqd = 0.08838834764831845f;  // 1/sqrt(128)
  float q0a = qs[lane * 2], q0b = qs[lane * 2 + 1];
  float q1a = qs[128 + lane * 2], q1b = qs[128 + lane * 2 + 1];
  float q2a = qs[256 + lane * 2], q2b = qs[256 + lane * 2 + 1];
  float q3a = qs[384 + lane * 2], q3b = qs[384 + lane * 2 + 1];

  for (int i = 0; i < 10; ++i) {
    int j = (blockIdx.x << 2) + wave + 52 * i;
    if (j > KSEL) continue;
    int sj = (j < KSEL) ? sidx[j] : SEQKV;
    const float* krow = (j < KSEL)
        ? key_cpu + ((((size_t)bh << 12) + sj) << 7)
        : key + ((size_t)bh << 7);
    float2 kk = ((const float2*)krow)[lane];
    float p0 = q0a * kk.x + q0b * kk.y;
    float p1 = q1a * kk.x + q1b * kk.y;
    float p2 = q2a * kk.x + q2b * kk.y;
    float p3 = q3a * kk.x + q3b * kk.y;
    for (int off = 32; off > 0; off >>= 1) {
      p0 += __shfl_down(p0, off);
      p1 += __shfl_down(p1, off);
      p2 += __shfl_down(p2, off);
      p3 += __shfl_down(p3, off);
    }
    if (lane == 0) {
      size_t lmb = (size_t)bh * 4 * SEQN + sj;
      s2_g[(bh * 4 + 0) * 520 + j] = p0 * rsqd + lm[lmb + 0 * SEQN];
      s2_g[(bh * 4 + 1) * 520 + j] = p1 * rsqd + lm[lmb + 1 * SEQN];
      s2_g[(bh * 4 + 2) * 520 + j] = p2 * rsqd + lm[lmb + 2 * SEQN];
      s2_g[(bh * 4 + 3) * 520 + j] = p3 * rsqd + lm[lmb + 3 * SEQN];
    }
  }
}

// ---------------------------------------------------------------------------
// Kernel 6: per (bh,p): full-softmax stats -> kv_weight; softmax over the
// 517 gathered scores; writes out_w, w_g, and initializes out with the
// (1-kvw)*mean_v_new term. grid 128, block 256.
// ---------------------------------------------------------------------------
__global__ __launch_bounds__(256) void k6_stats(
    const float* __restrict__ scores, const int* __restrict__ indices,
    const float* __restrict__ s2_g, const float* __restrict__ value,
    const float* __restrict__ mean_v,
    float* __restrict__ out_w, float* __restrict__ w_g,
    float* __restrict__ out) {
  int bhp = blockIdx.x;
  int bh = bhp >> 2;
  int t = threadIdx.x;
  __shared__ int sidx[KSEL];
  __shared__ float red[256];
  __shared__ float bc;

  for (int j = t; j < KSEL; j += 256) sidx[j] = indices[bh * KSEL + j];
  __syncthreads();

  const float* srow = scores + (size_t)bhp * SSTR;
  const float4* srow4 = (const float4*)srow;
  // max over 4097 (vectorized over the first 4096)
  float mx = -INFINITY;
  for (int i = t; i < 1024; i += 256) {
    float4 v = srow4[i];
    mx = fmaxf(mx, fmaxf(fmaxf(v.x, v.y), fmaxf(v.z, v.w)));
  }
  if (t == 0) mx = fmaxf(mx, srow[SEQKV]);
  red[t] = mx; __syncthreads();
  for (int st = 128; st > 0; st >>= 1) {
    if (t < st) red[t] = fmaxf(red[t], red[t + st]);
    __syncthreads();
  }
  float m = red[0]; __syncthreads();
  // total sum of exp
  float se = 0.f;
  for (int i = t; i < 1024; i += 256) {
    float4 v = srow4[i];
    se += expf(v.x - m) + expf(v.y - m) + expf(v.z - m) + expf(v.w - m);
  }
  if (t == 0) se += expf(srow[SEQKV] - m);
  red[t] = se; __syncthreads();
  for (int st = 128; st > 0; st >>= 1) {
    if (t < st) red[t] += red[t + st];
    __syncthreads();
  }
  float sumexp = red[0]; __syncthreads();
  // selected mass
  float ss = 0.f;
  for (int j = t; j < KSEL; j += 256) ss += expf(srow[sidx[j]] - m);
  red[t] = ss; __syncthreads();
  for (int st = 128; st > 0; st >>= 1) {
    if (t < st) red[t] += red[t + st];
    __syncthreads();
  }
  float kvw;
  if (t == 0) bc = (red[0] + expf(srow[SEQKV] - m)) / sumexp;
  __syncthreads();
  kvw = bc; __syncthreads();

  // softmax over 517 gathered scores
  const float* s2r = s2_g + (size_t)bhp * 520;
  float mx2 = -INFINITY;
  for (int j = t; j < KSEL + 1; j += 256) mx2 = fmaxf(mx2, s2r[j]);
  red[t] = mx2; __syncthreads();
  for (int st = 128; st > 0; st >>= 1) {
    if (t < st) red[t] = fmaxf(red[t], red[t + st]);
    __syncthreads();
  }
  float m2 = red[0]; __syncthreads();
  float se2 = 0.f;
  for (int j = t; j < KSEL + 1; j += 256) se2 += expf(s2r[j] - m2);
  red[t] = se2; __syncthreads();
  for (int st = 128; st > 0; st >>= 1) {
    if (t < st) red[t] += red[t + st];
    __syncthreads();
  }
  float inv = kvw / red[0];

  for (int j = t; j < KSEL + 1; j += 256) {
    float w = expf(s2r[j] - m2) * inv;
    out_w[(size_t)bhp * (KSEL + 1) + j] = w;
    w_g[(size_t)bhp * 520 + j] = w;
  }

  // initialize out with (1-kvw) * mean_v_new
  if (t < 128) {
    float vcur = value[((size_t)bh << 7) + t];
    float mvn = (mean_v[((size_t)bh << 7) + t] * 4096.f + vcur) / 4097.f;
    out[((size_t)bhp << 7) + t] = (1.f - kvw) * mvn;
  }
}

// ---------------------------------------------------------------------------
// Kernel 7: out += sum_j w[p][j] * V_g[j][:]. grid (9, 32 bh), block 256.
// ---------------------------------------------------------------------------
__global__ __launch_bounds__(256) void k7_wv(
    const float* __restrict__ value, const float* __restrict__ value_cpu,
    const int* __restrict__ indices, const float* __restrict__ w_g,
    float* __restrict__ out) {
  int bh = blockIdx.y;
  int c0 = blockIdx.x << 6;  // chunk start j
  int t = threadIdx.x;
  int d = t & 127, half = t >> 7;
  __shared__ int sidx[64];
  __shared__ float wsh[4][64];
  __shared__ float red[2][4][128];

  int nj = min(64, KSEL + 1 - c0);
  if (t < nj) {
    int j = c0 + t;
    sidx[t] = (j < KSEL) ? indices[bh * KSEL + j] : -1;
  }
  for (int i = t; i < 4 * 64; i += 256) {
    int p = i >> 6, jl = i & 63;
    wsh[p][jl] = (jl < nj) ? w_g[(size_t)(bh * 4 + p) * 520 + c0 + jl] : 0.f;
  }
  __syncthreads();

  float a0 = 0, a1 = 0, a2 = 0, a3 = 0;
  for (int jl = half; jl < nj; jl += 2) {
    int sj = sidx[jl];
    const float* vrow = (sj >= 0)
        ? value_cpu + ((((size_t)bh << 12) + sj) << 7)
        : value + ((size_t)bh << 7);
    float v = vrow[d];
    a0 += wsh[0][jl] * v;
    a1 += wsh[1][jl] * v;
    a2 += wsh[2][jl] * v;
    a3 += wsh[3][jl] * v;
  }
  red[half][0][d] = a0; red[half][1][d] = a1;
  red[half][2][d] = a2; red[half][3][d] = a3;
  __syncthreads();
  if (half == 0) {
#pragma unroll
    for (int p = 0; p < 4; ++p) {
      float s = red[0][p][d] + red[1][p][d];
      atomicAdd(&out[(size_t)(bh * 4 + p) * 128 + d], s);
    }
  }
}

// ---------------------------------------------------------------------------
extern "C" void kernel_launch(void* const* d_in, const int* in_sizes, int n_in,
                              void* d_out, int out_size, void* d_ws, size_t ws_size,
                              hipStream_t stream) {
  const float* query     = (const float*)d_in[0];
  const float* key       = (const float*)d_in[1];
  const float* value     = (const float*)d_in[2];
  const float* logmask   = (const float*)d_in[3];
  const float* key_cpu   = (const float*)d_in[4];
  const float* value_cpu = (const float*)d_in[5];
  const float* s_key_cpu = (const float*)d_in[6];
  const float* mean_v    = (const float*)d_in[7];

  float* out   = (float*)d_out;       // (4,32,1,128) = 16384 floats
  float* out_w = out + 16384;         // (4,32,1,517) = 66176 floats

  char* ws = (char*)d_ws;
  int*   indices   = (int*)(ws + 20480);          // 66048 B
  float* scores    = (float*)(ws + 86528);        // 128*4100*4 = 2099200 B
  float* tk        = (float*)(ws + 2185728);      // 524288 B
  float* s2_g      = (float*)(ws + 2710016);      // 266240 B
  float* w_g       = (float*)(ws + 2976256);      // 266240 B
  // total ws use: 3,242,496 bytes

  hipLaunchKernelGGL(k2_scores, dim3(8, NBH), dim3(256), 0, stream,
                     query, key, s_key_cpu, logmask, scores, tk);
  hipLaunchKernelGGL(k3_topk, dim3(NBH), dim3(256), 0, stream,
                     tk, indices);
  hipLaunchKernelGGL(k5_qk, dim3(13, NBH), dim3(256), 0, stream,
                     query, key, logmask, key_cpu, indices, s2_g);
  hipLaunchKernelGGL(k6_stats, dim3(128), dim3(256), 0, stream,
                     scores, indices, s2_g, value, mean_v, out_w, w_g, out);
  hipLaunchKernelGGL(k7_wv, dim3(9, NBH), dim3(256), 0, stream,
                     value, value_cpu, indices, w_g, out);
}

// Round 5
// 241.907 us; speedup vs baseline: 1.5140x; 1.0272x over previous
//
#include <hip/hip_runtime.h>
#include <hip/hip_bf16.h>
#include <math.h>

// Problem constants
#define NBH 32     // B*KVH = 4*8
#define HPKN 4
#define DN 128
#define SEQKV 4096
#define SEQN 4097
#define SSTR 4100  // padded score-row stride (keeps float4 alignment per row)
#define RANKN 32
#define KSEL 516   // K + SINK = 512 + 4
#define SINKN 4
#define LOCALK 128 // masked-local region starts at SEQKV - LOCALK = 3968
#define NMASK 132  // SINKN + LOCALK
#define NTOP 384   // KSEL - NMASK

// ---------------------------------------------------------------------------
// Kernel 2 (fused with old k1): per block, recompute rank-32 dim selection +
// scales from q via shuffle reductions, then approximate scores over this
// block's 512-position chunk. Also emits per-chunk softmax partials
// (max, sum-exp) per (bh,p) so k6 need not re-stream the score rows.
// Block x==0 also writes the current-token (s=4096) score.
// grid (8, 32 bh), block 256.
// ---------------------------------------------------------------------------
__global__ __launch_bounds__(256) void k2_scores(
    const float* __restrict__ q, const float* __restrict__ key,
    const float* __restrict__ skey, const float* __restrict__ lm,
    float* __restrict__ scores, float* __restrict__ tk,
    float2* __restrict__ partials) {
  int bh = blockIdx.y;
  int s0 = blockIdx.x << 9;
  int t = threadIdx.x;
  int wave = t >> 6, lane = t & 63;
  __shared__ float qv[4][128];
  __shared__ float absq[128];
  __shared__ int sel[RANKN];
  __shared__ float qp[4][RANKN];
  __shared__ float wred[4][4];

  // ---- selection prep (replicated per block) ----
  {
    float v0 = q[(size_t)bh * 512 + t];
    float v1 = q[(size_t)bh * 512 + 256 + t];
    qv[t >> 7][t & 127] = v0;
    qv[2 + (t >> 7)][t & 127] = v1;
  }
  __syncthreads();
  if (t < 128)
    absq[t] = fabsf(qv[0][t]) + fabsf(qv[1][t]) + fabsf(qv[2][t]) + fabsf(qv[3][t]);
  __syncthreads();
  if (t < 128) {
    float a = absq[t];
    int rank = 0;
    for (int e = 0; e < 128; ++e) {
      float ae = absq[e];
      rank += (ae > a) || (ae == a && e < t);
    }
    if (rank < RANKN) sel[rank] = t;
  }
  __syncthreads();
  // per-p (wave==p) full |q| sum and selected |q| sum via shuffles
  {
    float fa = fabsf(qv[wave][lane]) + fabsf(qv[wave][lane + 64]);
    for (int off = 32; off > 0; off >>= 1) fa += __shfl_down(fa, off);
    float full = __shfl(fa, 0);
    float qsel = (lane < RANKN) ? qv[wave][sel[lane]] : 0.f;
    float sv = fabsf(qsel);
    for (int off = 32; off > 0; off >>= 1) sv += __shfl_down(sv, off);
    float selsum = __shfl(sv, 0);
    float scale = sqrtf(selsum / full * 128.f);
    if (lane < RANKN) qp[wave][lane] = qsel / scale;
  }
  __syncthreads();

  // current-token score (block x==0 only; wave == p)
  if (blockIdx.x == 0) {
    float kv = (lane < RANKN) ? key[bh * 128 + sel[lane]] : 0.f;
    float pr = (lane < RANKN) ? qp[wave][lane] * kv : 0.f;
    for (int off = 32; off > 0; off >>= 1) pr += __shfl_down(pr, off);
    if (lane == 0)
      scores[(size_t)(bh * 4 + wave) * SSTR + SEQKV] =
          pr + lm[(size_t)(bh * 4 + wave) * SEQN + SEQKV];
  }

  // ---- main approximate-score loop over this chunk ----
  const float* kb = skey + (size_t)bh * 128 * 4096;
  float a00 = 0, a01 = 0, a02 = 0, a03 = 0;
  float a10 = 0, a11 = 0, a12 = 0, a13 = 0;
#pragma unroll 4
  for (int r = 0; r < RANKN; ++r) {
    const float* row = kb + ((size_t)sel[r] << 12) + s0;
    float k0 = row[t];
    float k1 = row[t + 256];
    float q0 = qp[0][r], q1 = qp[1][r], q2 = qp[2][r], q3 = qp[3][r];
    a00 += q0 * k0; a01 += q1 * k0; a02 += q2 * k0; a03 += q3 * k0;
    a10 += q0 * k1; a11 += q1 * k1; a12 += q2 * k1; a13 += q3 * k1;
  }
  float sc0[4] = {a00, a01, a02, a03};
  float sc1[4] = {a10, a11, a12, a13};
  {
    int s = s0 + t;
    float sum = 0;
#pragma unroll
    for (int p = 0; p < 4; ++p) {
      float sc = sc0[p] + lm[(size_t)(bh * 4 + p) * SEQN + s];
      sc0[p] = sc;
      scores[(size_t)(bh * 4 + p) * SSTR + s] = sc;
      sum += sc;
    }
    tk[(bh << 12) + s] = sum;
  }
  {
    int s = s0 + t + 256;
    float sum = 0;
#pragma unroll
    for (int p = 0; p < 4; ++p) {
      float sc = sc1[p] + lm[(size_t)(bh * 4 + p) * SEQN + s];
      sc1[p] = sc;
      scores[(size_t)(bh * 4 + p) * SSTR + s] = sc;
      sum += sc;
    }
    tk[(bh << 12) + s] = sum;
  }

  // ---- per-chunk softmax partials (max, sum-exp) per p ----
#pragma unroll
  for (int p = 0; p < 4; ++p) {
    float mx = fmaxf(sc0[p], sc1[p]);
    for (int off = 32; off > 0; off >>= 1) mx = fmaxf(mx, __shfl_down(mx, off));
    if (lane == 0) wred[wave][p] = mx;
  }
  __syncthreads();
  float bm[4];
#pragma unroll
  for (int p = 0; p < 4; ++p)
    bm[p] = fmaxf(fmaxf(wred[0][p], wred[1][p]), fmaxf(wred[2][p], wred[3][p]));
  __syncthreads();  // wred reuse
#pragma unroll
  for (int p = 0; p < 4; ++p) {
    float e = expf(sc0[p] - bm[p]) + expf(sc1[p] - bm[p]);
    for (int off = 32; off > 0; off >>= 1) e += __shfl_down(e, off);
    if (lane == 0) wred[wave][p] = e;
  }
  __syncthreads();
  if (t < 4) {
    float s = wred[0][t] + wred[1][t] + wred[2][t] + wred[3][t];
    partials[(size_t)(bh * 4 + t) * 8 + blockIdx.x] = make_float2(bm[t], s);
  }
}

// ---------------------------------------------------------------------------
// Kernel 3: top-384-of-3964 radix-select + hybrid register bitonic sort.
// Exact jax.lax.top_k(516) order: 132 masked (+inf) indices first
// (ascending), then the top-384 real sums descending, ties -> lower index.
// ---------------------------------------------------------------------------
__global__ __launch_bounds__(256) void k3_topk(
    const float* __restrict__ tk, int* __restrict__ indices) {
  int bh = blockIdx.x;
  int t = threadIdx.x;
  int lane = t & 63;
  __shared__ unsigned us[4096];               // sortable keys, 16 KB
  __shared__ unsigned hist[2048];             // 8 KB
  __shared__ unsigned long long binlist[2048];// 16 KB
  __shared__ unsigned long long selk[512];    // 4 KB
  __shared__ unsigned chunkSum[32];
  __shared__ int c1, c2, binB_s, nAbove_s, needed_s;

  for (int s = t; s < 4096; s += 256) {
    unsigned b = __float_as_uint(tk[(bh << 12) + s]);
    us[s] = (b & 0x80000000u) ? ~b : (b | 0x80000000u);
  }
  for (int i = t; i < 2048; i += 256) hist[i] = 0;
  if (t == 0) { c1 = 0; c2 = 0; }
  __syncthreads();

  // histogram of candidates s in [SINKN, SEQKV-LOCALK) on top 11 bits
  for (int s = SINKN + t; s < SEQKV - LOCALK; s += 256)
    atomicAdd(&hist[us[s] >> 21], 1u);
  __syncthreads();

  if (t < 32) {
    unsigned sum = 0;
    for (int i = 0; i < 64; ++i) sum += hist[t * 64 + i];
    chunkSum[t] = sum;
  }
  __syncthreads();

  if (t < 64) {
    int l = t;
    // suffix-inclusive sum over 32 chunk sums (higher chunk = larger keys)
    unsigned x = (l < 32) ? chunkSum[l] : 0;
    unsigned sfx = x;
    for (int off = 1; off < 64; off <<= 1) {
      unsigned y = __shfl_down(sfx, off);
      if (l + off < 64) sfx += y;
    }
    unsigned above = sfx - x;  // count in chunks strictly above mine
    bool hit = (l < 32) && (above < NTOP) && (above + x >= NTOP);
    unsigned long long mask = __ballot(hit);
    int C = __ffsll(mask) - 1;
    unsigned aboveC = __shfl(above, C);
    // refine within chunk C over its 64 bins
    unsigned h = hist[C * 64 + l];
    unsigned sfx2 = h;
    for (int off = 1; off < 64; off <<= 1) {
      unsigned y = __shfl_down(sfx2, off);
      if (l + off < 64) sfx2 += y;
    }
    unsigned above2 = aboveC + (sfx2 - h);
    bool hit2 = (above2 < NTOP) && (above2 + h >= NTOP);
    unsigned long long mask2 = __ballot(hit2);
    int lB = __ffsll(mask2) - 1;
    if (l == lB) {
      binB_s = C * 64 + l;
      nAbove_s = (int)above2;
      needed_s = NTOP - (int)above2;
    }
  }
  __syncthreads();
  unsigned B = (unsigned)binB_s;
  int nAbove = nAbove_s, needed = needed_s;

  // collect: definite winners -> selk, boundary-bin members -> binlist.
  // wave-aggregated compaction: one LDS atomic per wave per category.
  for (int s0 = SINKN; s0 < SEQKV - LOCALK; s0 += 256) {
    int s = s0 + t;
    bool valid = (s < SEQKV - LOCALK);
    unsigned u = valid ? us[s] : 0u;
    unsigned bin = u >> 21;
    bool win = valid && (bin > B);
    bool bnd = valid && (bin == B);
    unsigned long long mw = __ballot(win);
    unsigned long long mb = __ballot(bnd);
    int bw = 0, bb = 0;
    if (lane == 0) {
      if (mw) bw = atomicAdd(&c1, __popcll(mw));
      if (mb) bb = atomicAdd(&c2, __popcll(mb));
    }
    bw = __shfl(bw, 0);
    bb = __shfl(bb, 0);
    unsigned long long lmask = (1ULL << lane) - 1ULL;
    unsigned long long key = ((unsigned long long)u << 32) | (unsigned)(~s);
    if (win) selk[bw + __popcll(mw & lmask)] = key;
    if (bnd) {
      int pos = bb + __popcll(mb & lmask);
      if (pos < 2048) binlist[pos] = key;
    }
  }
  __syncthreads();
  int m2 = c2;
  int p2 = 1;
  while (p2 < m2) p2 <<= 1;
  for (int i = m2 + t; i < p2; i += 256) binlist[i] = 0ULL;
  __syncthreads();
  // bitonic sort (descending) of the boundary bin (small: ~hist[B] entries)
  for (int k = 2; k <= p2; k <<= 1)
    for (int j = k >> 1; j > 0; j >>= 1) {
      for (int i = t; i < p2; i += 256) {
        int ixj = i ^ j;
        if (ixj > i) {
          bool desc = ((i & k) == 0);
          unsigned long long a = binlist[i], bb2 = binlist[ixj];
          if ((a < bb2) == desc) { binlist[i] = bb2; binlist[ixj] = a; }
        }
      }
      __syncthreads();
    }
  for (int i = t; i < needed; i += 256) selk[nAbove + i] = binlist[i];
  for (int i = NTOP + t; i < 512; i += 256) selk[i] = 0ULL;
  __syncthreads();

  // hybrid register bitonic sort (descending) of 512:
  // thread t holds elements i0=t, i1=t+256. j=256 -> local swap,
  // j in {64,128} -> LDS exchange, j<64 -> shfl_xor in-wave.
  unsigned long long e0 = selk[t], e1 = selk[t + 256];
  int i1 = t + 256;
  for (int k = 2; k <= 512; k <<= 1) {
    for (int j = k >> 1; j > 0; j >>= 1) {
      if (j == 256) {
        if (e0 < e1) { unsigned long long tmp = e0; e0 = e1; e1 = tmp; }
      } else if (j >= 64) {
        selk[t] = e0; selk[i1] = e1;
        __syncthreads();
        unsigned long long p0 = selk[t ^ j], p1 = selk[i1 ^ j];
        __syncthreads();
        bool d0 = ((t & k) == 0), l0 = ((t & j) == 0);
        e0 = (d0 == l0) ? (e0 > p0 ? e0 : p0) : (e0 < p0 ? e0 : p0);
        bool d1 = ((i1 & k) == 0), l1 = ((i1 & j) == 0);
        e1 = (d1 == l1) ? (e1 > p1 ? e1 : p1) : (e1 < p1 ? e1 : p1);
      } else {
        unsigned long long p0 = __shfl_xor(e0, j);
        unsigned long long p1 = __shfl_xor(e1, j);
        bool d0 = ((t & k) == 0), l0 = ((t & j) == 0);
        e0 = (d0 == l0) ? (e0 > p0 ? e0 : p0) : (e0 < p0 ? e0 : p0);
        bool d1 = ((i1 & k) == 0);
        e1 = (d1 == l0) ? (e1 > p1 ? e1 : p1) : (e1 < p1 ? e1 : p1);
      }
    }
  }

  // emit: masked first (index-ascending), then top-384 descending
  if (t < SINKN) indices[bh * KSEL + t] = t;
  for (int i = t; i < LOCALK; i += 256)
    indices[bh * KSEL + SINKN + i] = (SEQKV - LOCALK) + i;
  indices[bh * KSEL + NMASK + t] = (int)(~(unsigned)(e0 & 0xFFFFFFFFu));
  if (t < NTOP - 256)
    indices[bh * KSEL + NMASK + 256 + t] = (int)(~(unsigned)(e1 & 0xFFFFFFFFu));
}

// ---------------------------------------------------------------------------
// Kernel 5: gathered QK^T scores. grid (13, 32 bh), block 256 = 4 waves.
// ---------------------------------------------------------------------------
__global__ __launch_bounds__(256) void k5_qk(
    const float* __restrict__ q, const float* __restrict__ key,
    const float* __restrict__ lm, const float* __restrict__ key_cpu,
    const int* __restrict__ indices, float* __restrict__ s2_g) {
  int bh = blockIdx.y;
  int t = threadIdx.x;
  int wave = t >> 6, lane = t & 63;
  __shared__ float qs[512];
  __shared__ int sidx[KSEL];
  qs[t] = q[((size_t)bh * 4 << 7) + t];
  qs[t + 256] = q[((size_t)bh * 4 << 7) + t + 256];
  for (int j = t; j < KSEL; j += 256) sidx[j] = indices[bh * KSEL + j];
  __syncthreads();

  const float rsqd = 0.08838834764831845f;  // 1/sqrt(128)
  float q0a = qs[lane * 2], q0b = qs[lane * 2 + 1];
  float q1a = qs[128 + lane * 2], q1b = qs[128 + lane * 2 + 1];
  float q2a = qs[256 + lane * 2], q2b = qs[256 + lane * 2 + 1];
  float q3a = qs[384 + lane * 2], q3b = qs[384 + lane * 2 + 1];

  for (int i = 0; i < 10; ++i) {
    int j = (blockIdx.x << 2) + wave + 52 * i;
    if (j > KSEL) continue;
    int sj = (j < KSEL) ? sidx[j] : SEQKV;
    const float* krow = (j < KSEL)
        ? key_cpu + ((((size_t)bh << 12) + sj) << 7)
        : key + ((size_t)bh << 7);
    float2 kk = ((const float2*)krow)[lane];
    float p0 = q0a * kk.x + q0b * kk.y;
    float p1 = q1a * kk.x + q1b * kk.y;
    float p2 = q2a * kk.x + q2b * kk.y;
    float p3 = q3a * kk.x + q3b * kk.y;
    for (int off = 32; off > 0; off >>= 1) {
      p0 += __shfl_down(p0, off);
      p1 += __shfl_down(p1, off);
      p2 += __shfl_down(p2, off);
      p3 += __shfl_down(p3, off);
    }
    if (lane == 0) {
      size_t lmb = (size_t)bh * 4 * SEQN + sj;
      s2_g[(bh * 4 + 0) * 520 + j] = p0 * rsqd + lm[lmb + 0 * SEQN];
      s2_g[(bh * 4 + 1) * 520 + j] = p1 * rsqd + lm[lmb + 1 * SEQN];
      s2_g[(bh * 4 + 2) * 520 + j] = p2 * rsqd + lm[lmb + 2 * SEQN];
      s2_g[(bh * 4 + 3) * 520 + j] = p3 * rsqd + lm[lmb + 3 * SEQN];
    }
  }
}

// ---------------------------------------------------------------------------
// Kernel 6: per (bh,p): merge k2's softmax partials -> kv_weight (with the
// selected-mass gather); softmax over the 517 gathered scores; writes out_w,
// w_g, and initializes out with the (1-kvw)*mean_v_new term.
// grid 128, block 256.
// ---------------------------------------------------------------------------
__global__ __launch_bounds__(256) void k6_stats(
    const float* __restrict__ scores, const float2* __restrict__ partials,
    const int* __restrict__ indices, const float* __restrict__ s2_g,
    const float* __restrict__ value, const float* __restrict__ mean_v,
    float* __restrict__ out_w, float* __restrict__ w_g,
    float* __restrict__ out) {
  int bhp = blockIdx.x;
  int bh = bhp >> 2;
  int t = threadIdx.x;
  __shared__ int sidx[KSEL];
  __shared__ float red[256];
  __shared__ float bc;

  for (int j = t; j < KSEL; j += 256) sidx[j] = indices[bh * KSEL + j];
  __syncthreads();

  const float* srow = scores + (size_t)bhp * SSTR;
  float cur = srow[SEQKV];

  // merge the 8 per-chunk partials (uniform loads, all threads)
  float m = cur, sumexp;
  {
    float2 pc[8];
#pragma unroll
    for (int c = 0; c < 8; ++c) {
      pc[c] = partials[(size_t)bhp * 8 + c];
      m = fmaxf(m, pc[c].x);
    }
    float s = expf(cur - m);
#pragma unroll
    for (int c = 0; c < 8; ++c) s += pc[c].y * expf(pc[c].x - m);
    sumexp = s;
  }

  // selected mass (gather over the 516 selected positions)
  float ss = 0.f;
  for (int j = t; j < KSEL; j += 256) ss += expf(srow[sidx[j]] - m);
  red[t] = ss; __syncthreads();
  for (int st = 128; st > 0; st >>= 1) {
    if (t < st) red[t] += red[t + st];
    __syncthreads();
  }
  float kvw;
  if (t == 0) bc = (red[0] + expf(cur - m)) / sumexp;
  __syncthreads();
  kvw = bc; __syncthreads();

  // softmax over 517 gathered scores
  const float* s2r = s2_g + (size_t)bhp * 520;
  float mx2 = -INFINITY;
  for (int j = t; j < KSEL + 1; j += 256) mx2 = fmaxf(mx2, s2r[j]);
  red[t] = mx2; __syncthreads();
  for (int st = 128; st > 0; st >>= 1) {
    if (t < st) red[t] = fmaxf(red[t], red[t + st]);
    __syncthreads();
  }
  float m2 = red[0]; __syncthreads();
  float se2 = 0.f;
  for (int j = t; j < KSEL + 1; j += 256) se2 += expf(s2r[j] - m2);
  red[t] = se2; __syncthreads();
  for (int st = 128; st > 0; st >>= 1) {
    if (t < st) red[t] += red[t + st];
    __syncthreads();
  }
  float inv = kvw / red[0];

  for (int j = t; j < KSEL + 1; j += 256) {
    float w = expf(s2r[j] - m2) * inv;
    out_w[(size_t)bhp * (KSEL + 1) + j] = w;
    w_g[(size_t)bhp * 520 + j] = w;
  }

  // initialize out with (1-kvw) * mean_v_new
  if (t < 128) {
    float vcur = value[((size_t)bh << 7) + t];
    float mvn = (mean_v[((size_t)bh << 7) + t] * 4096.f + vcur) / 4097.f;
    out[((size_t)bhp << 7) + t] = (1.f - kvw) * mvn;
  }
}

// ---------------------------------------------------------------------------
// Kernel 7: out += sum_j w[p][j] * V_g[j][:]. grid (9, 32 bh), block 256.
// ---------------------------------------------------------------------------
__global__ __launch_bounds__(256) void k7_wv(
    const float* __restrict__ value, const float* __restrict__ value_cpu,
    const int* __restrict__ indices, const float* __restrict__ w_g,
    float* __restrict__ out) {
  int bh = blockIdx.y;
  int c0 = blockIdx.x << 6;  // chunk start j
  int t = threadIdx.x;
  int d = t & 127, half = t >> 7;
  __shared__ int sidx[64];
  __shared__ float wsh[4][64];
  __shared__ float red[2][4][128];

  int nj = min(64, KSEL + 1 - c0);
  if (t < nj) {
    int j = c0 + t;
    sidx[t] = (j < KSEL) ? indices[bh * KSEL + j] : -1;
  }
  for (int i = t; i < 4 * 64; i += 256) {
    int p = i >> 6, jl = i & 63;
    wsh[p][jl] = (jl < nj) ? w_g[(size_t)(bh * 4 + p) * 520 + c0 + jl] : 0.f;
  }
  __syncthreads();

  float a0 = 0, a1 = 0, a2 = 0, a3 = 0;
  for (int jl = half; jl < nj; jl += 2) {
    int sj = sidx[jl];
    const float* vrow = (sj >= 0)
        ? value_cpu + ((((size_t)bh << 12) + sj) << 7)
        : value + ((size_t)bh << 7);
    float v = vrow[d];
    a0 += wsh[0][jl] * v;
    a1 += wsh[1][jl] * v;
    a2 += wsh[2][jl] * v;
    a3 += wsh[3][jl] * v;
  }
  red[half][0][d] = a0; red[half][1][d] = a1;
  red[half][2][d] = a2; red[half][3][d] = a3;
  __syncthreads();
  if (half == 0) {
#pragma unroll
    for (int p = 0; p < 4; ++p) {
      float s = red[0][p][d] + red[1][p][d];
      atomicAdd(&out[(size_t)(bh * 4 + p) * 128 + d], s);
    }
  }
}

// ---------------------------------------------------------------------------
extern "C" void kernel_launch(void* const* d_in, const int* in_sizes, int n_in,
                              void* d_out, int out_size, void* d_ws, size_t ws_size,
                              hipStream_t stream) {
  const float* query     = (const float*)d_in[0];
  const float* key       = (const float*)d_in[1];
  const float* value     = (const float*)d_in[2];
  const float* logmask   = (const float*)d_in[3];
  const float* key_cpu   = (const float*)d_in[4];
  const float* value_cpu = (const float*)d_in[5];
  const float* s_key_cpu = (const float*)d_in[6];
  const float* mean_v    = (const float*)d_in[7];

  float* out   = (float*)d_out;       // (4,32,1,128) = 16384 floats
  float* out_w = out + 16384;         // (4,32,1,517) = 66176 floats

  char* ws = (char*)d_ws;
  int*    indices  = (int*)(ws + 20480);          // 66048 B
  float*  scores   = (float*)(ws + 86528);        // 128*4100*4 = 2099200 B
  float*  tk       = (float*)(ws + 2185728);      // 524288 B
  float*  s2_g     = (float*)(ws + 2710016);      // 266240 B
  float*  w_g      = (float*)(ws + 2976256);      // 266240 B
  float2* partials = (float2*)(ws + 3242496);     // 128*8*8 = 8192 B
  // total ws use: 3,250,688 bytes

  hipLaunchKernelGGL(k2_scores, dim3(8, NBH), dim3(256), 0, stream,
                     query, key, s_key_cpu, logmask, scores, tk, partials);
  hipLaunchKernelGGL(k3_topk, dim3(NBH), dim3(256), 0, stream,
                     tk, indices);
  hipLaunchKernelGGL(k5_qk, dim3(13, NBH), dim3(256), 0, stream,
                     query, key, logmask, key_cpu, indices, s2_g);
  hipLaunchKernelGGL(k6_stats, dim3(128), dim3(256), 0, stream,
                     scores, partials, indices, s2_g, value, mean_v,
                     out_w, w_g, out);
  hipLaunchKernelGGL(k7_wv, dim3(9, NBH), dim3(256), 0, stream,
                     value, value_cpu, indices, w_g, out);
}

// Round 6
// 229.018 us; speedup vs baseline: 1.5993x; 1.0563x over previous
//
#include <hip/hip_runtime.h>
#include <hip/hip_bf16.h>
#include <math.h>

// Problem constants
#define NBH 32     // B*KVH = 4*8
#define HPKN 4
#define DN 128
#define SEQKV 4096
#define SEQN 4097
#define SSTR 4100  // padded score-row stride (keeps float4 alignment per row)
#define RANKN 32
#define KSEL 516   // K + SINK = 512 + 4
#define SINKN 4
#define LOCALK 128 // masked-local region starts at SEQKV - LOCALK = 3968
#define NMASK 132  // SINKN + LOCALK
#define NTOP 384   // KSEL - NMASK
#define NCHUNK 16  // k2 position-chunks per bh

// ---------------------------------------------------------------------------
// Kernel 2: per block, recompute rank-32 dim selection + scales from q via
// shuffle reductions, then approximate scores over this block's 256-position
// chunk. Emits per-chunk softmax partials (max, sum-exp) per (bh,p).
// Block x==0 also writes the current-token (s=4096) score.
// grid (16, 32 bh), block 256.
// ---------------------------------------------------------------------------
__global__ __launch_bounds__(256) void k2_scores(
    const float* __restrict__ q, const float* __restrict__ key,
    const float* __restrict__ skey, const float* __restrict__ lm,
    float* __restrict__ scores, float* __restrict__ tk,
    float2* __restrict__ partials) {
  int bh = blockIdx.y;
  int s0 = blockIdx.x << 8;
  int t = threadIdx.x;
  int wave = t >> 6, lane = t & 63;
  __shared__ float qv[4][128];
  __shared__ float absq[128];
  __shared__ int sel[RANKN];
  __shared__ float qp[4][RANKN];
  __shared__ float wred[4][4];

  // ---- selection prep (replicated per block) ----
  {
    float v0 = q[(size_t)bh * 512 + t];
    float v1 = q[(size_t)bh * 512 + 256 + t];
    qv[t >> 7][t & 127] = v0;
    qv[2 + (t >> 7)][t & 127] = v1;
  }
  __syncthreads();
  if (t < 128)
    absq[t] = fabsf(qv[0][t]) + fabsf(qv[1][t]) + fabsf(qv[2][t]) + fabsf(qv[3][t]);
  __syncthreads();
  if (t < 128) {
    float a = absq[t];
    int rank = 0;
    for (int e = 0; e < 128; ++e) {
      float ae = absq[e];
      rank += (ae > a) || (ae == a && e < t);
    }
    if (rank < RANKN) sel[rank] = t;
  }
  __syncthreads();
  // per-p (wave==p) full |q| sum and selected |q| sum via shuffles
  {
    float fa = fabsf(qv[wave][lane]) + fabsf(qv[wave][lane + 64]);
    for (int off = 32; off > 0; off >>= 1) fa += __shfl_down(fa, off);
    float full = __shfl(fa, 0);
    float qsel = (lane < RANKN) ? qv[wave][sel[lane]] : 0.f;
    float sv = fabsf(qsel);
    for (int off = 32; off > 0; off >>= 1) sv += __shfl_down(sv, off);
    float selsum = __shfl(sv, 0);
    float scale = sqrtf(selsum / full * 128.f);
    if (lane < RANKN) qp[wave][lane] = qsel / scale;
  }
  __syncthreads();

  // current-token score (block x==0 only; wave == p)
  if (blockIdx.x == 0) {
    float kv = (lane < RANKN) ? key[bh * 128 + sel[lane]] : 0.f;
    float pr = (lane < RANKN) ? qp[wave][lane] * kv : 0.f;
    for (int off = 32; off > 0; off >>= 1) pr += __shfl_down(pr, off);
    if (lane == 0)
      scores[(size_t)(bh * 4 + wave) * SSTR + SEQKV] =
          pr + lm[(size_t)(bh * 4 + wave) * SEQN + SEQKV];
  }

  // ---- main approximate-score loop over this 256-position chunk ----
  const float* kb = skey + (size_t)bh * 128 * 4096;
  float a0 = 0, a1 = 0, a2 = 0, a3 = 0;
#pragma unroll 8
  for (int r = 0; r < RANKN; ++r) {
    float k0 = kb[((size_t)sel[r] << 12) + s0 + t];
    a0 += qp[0][r] * k0;
    a1 += qp[1][r] * k0;
    a2 += qp[2][r] * k0;
    a3 += qp[3][r] * k0;
  }
  float sc[4];
  {
    int s = s0 + t;
    sc[0] = a0 + lm[(size_t)(bh * 4 + 0) * SEQN + s];
    sc[1] = a1 + lm[(size_t)(bh * 4 + 1) * SEQN + s];
    sc[2] = a2 + lm[(size_t)(bh * 4 + 2) * SEQN + s];
    sc[3] = a3 + lm[(size_t)(bh * 4 + 3) * SEQN + s];
    float sum = sc[0] + sc[1] + sc[2] + sc[3];
#pragma unroll
    for (int p = 0; p < 4; ++p)
      scores[(size_t)(bh * 4 + p) * SSTR + s] = sc[p];
    tk[(bh << 12) + s] = sum;
  }

  // ---- per-chunk softmax partials (max, sum-exp) per p ----
#pragma unroll
  for (int p = 0; p < 4; ++p) {
    float mx = sc[p];
    for (int off = 32; off > 0; off >>= 1) mx = fmaxf(mx, __shfl_down(mx, off));
    if (lane == 0) wred[wave][p] = mx;
  }
  __syncthreads();
  float bm[4];
#pragma unroll
  for (int p = 0; p < 4; ++p)
    bm[p] = fmaxf(fmaxf(wred[0][p], wred[1][p]), fmaxf(wred[2][p], wred[3][p]));
  __syncthreads();  // wred reuse
#pragma unroll
  for (int p = 0; p < 4; ++p) {
    float e = expf(sc[p] - bm[p]);
    for (int off = 32; off > 0; off >>= 1) e += __shfl_down(e, off);
    if (lane == 0) wred[wave][p] = e;
  }
  __syncthreads();
  if (t < 4) {
    float s = wred[0][t] + wred[1][t] + wred[2][t] + wred[3][t];
    partials[(size_t)(bh * 4 + t) * NCHUNK + blockIdx.x] = make_float2(bm[t], s);
  }
}

// ---------------------------------------------------------------------------
// Kernel 3: top-384-of-3964 radix-select + hybrid register bitonic sort.
// Exact jax.lax.top_k(516) order: 132 masked (+inf) indices first
// (ascending), then the top-384 real sums descending, ties -> lower index.
// ---------------------------------------------------------------------------
__global__ __launch_bounds__(256) void k3_topk(
    const float* __restrict__ tk, int* __restrict__ indices) {
  int bh = blockIdx.x;
  int t = threadIdx.x;
  int lane = t & 63;
  __shared__ unsigned us[4096];               // sortable keys, 16 KB
  __shared__ unsigned hist[2048];             // 8 KB
  __shared__ unsigned long long binlist[2048];// 16 KB
  __shared__ unsigned long long selk[512];    // 4 KB
  __shared__ unsigned chunkSum[32];
  __shared__ int c1, c2, binB_s, nAbove_s, needed_s;

  {
    const float4* tk4 = (const float4*)(tk + (bh << 12));
    for (int i = t; i < 1024; i += 256) {
      float4 v = tk4[i];
      unsigned b0 = __float_as_uint(v.x), b1 = __float_as_uint(v.y);
      unsigned b2 = __float_as_uint(v.z), b3 = __float_as_uint(v.w);
      us[i * 4 + 0] = (b0 & 0x80000000u) ? ~b0 : (b0 | 0x80000000u);
      us[i * 4 + 1] = (b1 & 0x80000000u) ? ~b1 : (b1 | 0x80000000u);
      us[i * 4 + 2] = (b2 & 0x80000000u) ? ~b2 : (b2 | 0x80000000u);
      us[i * 4 + 3] = (b3 & 0x80000000u) ? ~b3 : (b3 | 0x80000000u);
    }
  }
  for (int i = t; i < 2048; i += 256) hist[i] = 0;
  if (t == 0) { c1 = 0; c2 = 0; }
  __syncthreads();

  // histogram of candidates s in [SINKN, SEQKV-LOCALK) on top 11 bits
  for (int s = SINKN + t; s < SEQKV - LOCALK; s += 256)
    atomicAdd(&hist[us[s] >> 21], 1u);
  __syncthreads();

  if (t < 32) {
    unsigned sum = 0;
    for (int i = 0; i < 64; ++i) sum += hist[t * 64 + i];
    chunkSum[t] = sum;
  }
  __syncthreads();

  if (t < 64) {
    int l = t;
    // suffix-inclusive sum over 32 chunk sums (higher chunk = larger keys)
    unsigned x = (l < 32) ? chunkSum[l] : 0;
    unsigned sfx = x;
    for (int off = 1; off < 64; off <<= 1) {
      unsigned y = __shfl_down(sfx, off);
      if (l + off < 64) sfx += y;
    }
    unsigned above = sfx - x;  // count in chunks strictly above mine
    bool hit = (l < 32) && (above < NTOP) && (above + x >= NTOP);
    unsigned long long mask = __ballot(hit);
    int C = __ffsll(mask) - 1;
    unsigned aboveC = __shfl(above, C);
    // refine within chunk C over its 64 bins
    unsigned h = hist[C * 64 + l];
    unsigned sfx2 = h;
    for (int off = 1; off < 64; off <<= 1) {
      unsigned y = __shfl_down(sfx2, off);
      if (l + off < 64) sfx2 += y;
    }
    unsigned above2 = aboveC + (sfx2 - h);
    bool hit2 = (above2 < NTOP) && (above2 + h >= NTOP);
    unsigned long long mask2 = __ballot(hit2);
    int lB = __ffsll(mask2) - 1;
    if (l == lB) {
      binB_s = C * 64 + l;
      nAbove_s = (int)above2;
      needed_s = NTOP - (int)above2;
    }
  }
  __syncthreads();
  unsigned B = (unsigned)binB_s;
  int nAbove = nAbove_s, needed = needed_s;

  // collect: definite winners -> selk, boundary-bin members -> binlist.
  // wave-aggregated compaction: one LDS atomic per wave per category.
  for (int s0 = SINKN; s0 < SEQKV - LOCALK; s0 += 256) {
    int s = s0 + t;
    bool valid = (s < SEQKV - LOCALK);
    unsigned u = valid ? us[s] : 0u;
    unsigned bin = u >> 21;
    bool win = valid && (bin > B);
    bool bnd = valid && (bin == B);
    unsigned long long mw = __ballot(win);
    unsigned long long mb = __ballot(bnd);
    int bw = 0, bb = 0;
    if (lane == 0) {
      if (mw) bw = atomicAdd(&c1, __popcll(mw));
      if (mb) bb = atomicAdd(&c2, __popcll(mb));
    }
    bw = __shfl(bw, 0);
    bb = __shfl(bb, 0);
    unsigned long long lmask = (1ULL << lane) - 1ULL;
    unsigned long long key = ((unsigned long long)u << 32) | (unsigned)(~s);
    if (win) selk[bw + __popcll(mw & lmask)] = key;
    if (bnd) {
      int pos = bb + __popcll(mb & lmask);
      if (pos < 2048) binlist[pos] = key;
    }
  }
  __syncthreads();
  int m2 = c2;
  int p2 = 1;
  while (p2 < m2) p2 <<= 1;
  for (int i = m2 + t; i < p2; i += 256) binlist[i] = 0ULL;
  __syncthreads();
  // bitonic sort (descending) of the boundary bin (small: ~hist[B] entries)
  for (int k = 2; k <= p2; k <<= 1)
    for (int j = k >> 1; j > 0; j >>= 1) {
      for (int i = t; i < p2; i += 256) {
        int ixj = i ^ j;
        if (ixj > i) {
          bool desc = ((i & k) == 0);
          unsigned long long a = binlist[i], bb2 = binlist[ixj];
          if ((a < bb2) == desc) { binlist[i] = bb2; binlist[ixj] = a; }
        }
      }
      __syncthreads();
    }
  for (int i = t; i < needed; i += 256) selk[nAbove + i] = binlist[i];
  for (int i = NTOP + t; i < 512; i += 256) selk[i] = 0ULL;
  __syncthreads();

  // hybrid register bitonic sort (descending) of 512:
  // thread t holds elements i0=t, i1=t+256. j=256 -> local swap,
  // j in {64,128} -> LDS exchange, j<64 -> shfl_xor in-wave.
  unsigned long long e0 = selk[t], e1 = selk[t + 256];
  int i1 = t + 256;
  for (int k = 2; k <= 512; k <<= 1) {
    for (int j = k >> 1; j > 0; j >>= 1) {
      if (j == 256) {
        if (e0 < e1) { unsigned long long tmp = e0; e0 = e1; e1 = tmp; }
      } else if (j >= 64) {
        selk[t] = e0; selk[i1] = e1;
        __syncthreads();
        unsigned long long p0 = selk[t ^ j], p1 = selk[i1 ^ j];
        __syncthreads();
        bool d0 = ((t & k) == 0), l0 = ((t & j) == 0);
        e0 = (d0 == l0) ? (e0 > p0 ? e0 : p0) : (e0 < p0 ? e0 : p0);
        bool d1 = ((i1 & k) == 0), l1 = ((i1 & j) == 0);
        e1 = (d1 == l1) ? (e1 > p1 ? e1 : p1) : (e1 < p1 ? e1 : p1);
      } else {
        unsigned long long p0 = __shfl_xor(e0, j);
        unsigned long long p1 = __shfl_xor(e1, j);
        bool d0 = ((t & k) == 0), l0 = ((t & j) == 0);
        e0 = (d0 == l0) ? (e0 > p0 ? e0 : p0) : (e0 < p0 ? e0 : p0);
        bool d1 = ((i1 & k) == 0);
        e1 = (d1 == l0) ? (e1 > p1 ? e1 : p1) : (e1 < p1 ? e1 : p1);
      }
    }
  }

  // emit: masked first (index-ascending), then top-384 descending
  if (t < SINKN) indices[bh * KSEL + t] = t;
  for (int i = t; i < LOCALK; i += 256)
    indices[bh * KSEL + SINKN + i] = (SEQKV - LOCALK) + i;
  indices[bh * KSEL + NMASK + t] = (int)(~(unsigned)(e0 & 0xFFFFFFFFu));
  if (t < NTOP - 256)
    indices[bh * KSEL + NMASK + 256 + t] = (int)(~(unsigned)(e1 & 0xFFFFFFFFu));
}

// ---------------------------------------------------------------------------
// Kernel 5: gathered QK^T scores. grid (26, 32 bh), block 256 = 4 waves.
// ---------------------------------------------------------------------------
__global__ __launch_bounds__(256) void k5_qk(
    const float* __restrict__ q, const float* __restrict__ key,
    const float* __restrict__ lm, const float* __restrict__ key_cpu,
    const int* __restrict__ indices, float* __restrict__ s2_g) {
  int bh = blockIdx.y;
  int t = threadIdx.x;
  int wave = t >> 6, lane = t & 63;
  __shared__ float qs[512];
  __shared__ int sidx[KSEL];
  qs[t] = q[((size_t)bh * 4 << 7) + t];
  qs[t + 256] = q[((size_t)bh * 4 << 7) + t + 256];
  for (int j = t; j < KSEL; j += 256) sidx[j] = indices[bh * KSEL + j];
  __syncthreads();

  const float rsqd = 0.08838834764831845f;  // 1/sqrt(128)
  float q0a = qs[lane * 2], q0b = qs[lane * 2 + 1];
  float q1a = qs[128 + lane * 2], q1b = qs[128 + lane * 2 + 1];
  float q2a = qs[256 + lane * 2], q2b = qs[256 + lane * 2 + 1];
  float q3a = qs[384 + lane * 2], q3b = qs[384 + lane * 2 + 1];

  for (int i = 0; i < 5; ++i) {
    int j = (blockIdx.x << 2) + wave + 104 * i;
    if (j > KSEL) continue;
    int sj = (j < KSEL) ? sidx[j] : SEQKV;
    const float* krow = (j < KSEL)
        ? key_cpu + ((((size_t)bh << 12) + sj) << 7)
        : key + ((size_t)bh << 7);
    float2 kk = ((const float2*)krow)[lane];
    float p0 = q0a * kk.x + q0b * kk.y;
    float p1 = q1a * kk.x + q1b * kk.y;
    float p2 = q2a * kk.x + q2b * kk.y;
    float p3 = q3a * kk.x + q3b * kk.y;
    for (int off = 32; off > 0; off >>= 1) {
      p0 += __shfl_down(p0, off);
      p1 += __shfl_down(p1, off);
      p2 += __shfl_down(p2, off);
      p3 += __shfl_down(p3, off);
    }
    if (lane == 0) {
      size_t lmb = (size_t)bh * 4 * SEQN + sj;
      s2_g[(bh * 4 + 0) * 520 + j] = p0 * rsqd + lm[lmb + 0 * SEQN];
      s2_g[(bh * 4 + 1) * 520 + j] = p1 * rsqd + lm[lmb + 1 * SEQN];
      s2_g[(bh * 4 + 2) * 520 + j] = p2 * rsqd + lm[lmb + 2 * SEQN];
      s2_g[(bh * 4 + 3) * 520 + j] = p3 * rsqd + lm[lmb + 3 * SEQN];
    }
  }
}

// ---------------------------------------------------------------------------
// Kernel 6: per (bh,p): merge k2's softmax partials -> kv_weight (with the
// selected-mass gather); softmax over the 517 gathered scores; writes out_w,
// w_g, and initializes out with the (1-kvw)*mean_v_new term.
// grid 128, block 256.
// ---------------------------------------------------------------------------
__global__ __launch_bounds__(256) void k6_stats(
    const float* __restrict__ scores, const float2* __restrict__ partials,
    const int* __restrict__ indices, const float* __restrict__ s2_g,
    const float* __restrict__ value, const float* __restrict__ mean_v,
    float* __restrict__ out_w, float* __restrict__ w_g,
    float* __restrict__ out) {
  int bhp = blockIdx.x;
  int bh = bhp >> 2;
  int t = threadIdx.x;
  __shared__ int sidx[KSEL];
  __shared__ float red[256];
  __shared__ float bc;

  for (int j = t; j < KSEL; j += 256) sidx[j] = indices[bh * KSEL + j];
  __syncthreads();

  const float* srow = scores + (size_t)bhp * SSTR;
  float cur = srow[SEQKV];

  // merge the 16 per-chunk partials (uniform loads, all threads)
  float m = cur, sumexp;
  {
    float2 pc[NCHUNK];
#pragma unroll
    for (int c = 0; c < NCHUNK; ++c) {
      pc[c] = partials[(size_t)bhp * NCHUNK + c];
      m = fmaxf(m, pc[c].x);
    }
    float s = expf(cur - m);
#pragma unroll
    for (int c = 0; c < NCHUNK; ++c) s += pc[c].y * expf(pc[c].x - m);
    sumexp = s;
  }

  // selected mass (gather over the 516 selected positions)
  float ss = 0.f;
  for (int j = t; j < KSEL; j += 256) ss += expf(srow[sidx[j]] - m);
  red[t] = ss; __syncthreads();
  for (int st = 128; st > 0; st >>= 1) {
    if (t < st) red[t] += red[t + st];
    __syncthreads();
  }
  float kvw;
  if (t == 0) bc = (red[0] + expf(cur - m)) / sumexp;
  __syncthreads();
  kvw = bc; __syncthreads();

  // softmax over 517 gathered scores
  const float* s2r = s2_g + (size_t)bhp * 520;
  float mx2 = -INFINITY;
  for (int j = t; j < KSEL + 1; j += 256) mx2 = fmaxf(mx2, s2r[j]);
  red[t] = mx2; __syncthreads();
  for (int st = 128; st > 0; st >>= 1) {
    if (t < st) red[t] = fmaxf(red[t], red[t + st]);
    __syncthreads();
  }
  float m2 = red[0]; __syncthreads();
  float se2 = 0.f;
  for (int j = t; j < KSEL + 1; j += 256) se2 += expf(s2r[j] - m2);
  red[t] = se2; __syncthreads();
  for (int st = 128; st > 0; st >>= 1) {
    if (t < st) red[t] += red[t + st];
    __syncthreads();
  }
  float inv = kvw / red[0];

  for (int j = t; j < KSEL + 1; j += 256) {
    float w = expf(s2r[j] - m2) * inv;
    out_w[(size_t)bhp * (KSEL + 1) + j] = w;
    w_g[(size_t)bhp * 520 + j] = w;
  }

  // initialize out with (1-kvw) * mean_v_new
  if (t < 128) {
    float vcur = value[((size_t)bh << 7) + t];
    float mvn = (mean_v[((size_t)bh << 7) + t] * 4096.f + vcur) / 4097.f;
    out[((size_t)bhp << 7) + t] = (1.f - kvw) * mvn;
  }
}

// ---------------------------------------------------------------------------
// Kernel 7: out += sum_j w[p][j] * V_g[j][:]. grid (17, 32 bh), block 256
// (2 j-lanes x 128 d), 32 j per chunk. atomicAdd accumulation into out.
// ---------------------------------------------------------------------------
__global__ __launch_bounds__(256) void k7_wv(
    const float* __restrict__ value, const float* __restrict__ value_cpu,
    const int* __restrict__ indices, const float* __restrict__ w_g,
    float* __restrict__ out) {
  int bh = blockIdx.y;
  int c0 = blockIdx.x << 5;  // chunk start j
  int t = threadIdx.x;
  int d = t & 127, half = t >> 7;
  __shared__ int sidx[32];
  __shared__ float wsh[4][32];
  __shared__ float red[2][4][128];

  int nj = min(32, KSEL + 1 - c0);
  if (t < nj) {
    int j = c0 + t;
    sidx[t] = (j < KSEL) ? indices[bh * KSEL + j] : -1;
  }
  if (t < 128) {
    int p = t >> 5, jl = t & 31;
    wsh[p][jl] = (jl < nj) ? w_g[(size_t)(bh * 4 + p) * 520 + c0 + jl] : 0.f;
  }
  __syncthreads();

  float a0 = 0, a1 = 0, a2 = 0, a3 = 0;
  for (int jl = half; jl < nj; jl += 2) {
    int sj = sidx[jl];
    const float* vrow = (sj >= 0)
        ? value_cpu + ((((size_t)bh << 12) + sj) << 7)
        : value + ((size_t)bh << 7);
    float v = vrow[d];
    a0 += wsh[0][jl] * v;
    a1 += wsh[1][jl] * v;
    a2 += wsh[2][jl] * v;
    a3 += wsh[3][jl] * v;
  }
  red[half][0][d] = a0; red[half][1][d] = a1;
  red[half][2][d] = a2; red[half][3][d] = a3;
  __syncthreads();
  if (half == 0) {
#pragma unroll
    for (int p = 0; p < 4; ++p) {
      float s = red[0][p][d] + red[1][p][d];
      atomicAdd(&out[(size_t)(bh * 4 + p) * 128 + d], s);
    }
  }
}

// ---------------------------------------------------------------------------
extern "C" void kernel_launch(void* const* d_in, const int* in_sizes, int n_in,
                              void* d_out, int out_size, void* d_ws, size_t ws_size,
                              hipStream_t stream) {
  const float* query     = (const float*)d_in[0];
  const float* key       = (const float*)d_in[1];
  const float* value     = (const float*)d_in[2];
  const float* logmask   = (const float*)d_in[3];
  const float* key_cpu   = (const float*)d_in[4];
  const float* value_cpu = (const float*)d_in[5];
  const float* s_key_cpu = (const float*)d_in[6];
  const float* mean_v    = (const float*)d_in[7];

  float* out   = (float*)d_out;       // (4,32,1,128) = 16384 floats
  float* out_w = out + 16384;         // (4,32,1,517) = 66176 floats

  char* ws = (char*)d_ws;
  int*    indices  = (int*)(ws + 20480);          // 66048 B
  float*  scores   = (float*)(ws + 86528);        // 128*4100*4 = 2099200 B
  float*  tk       = (float*)(ws + 2185728);      // 524288 B
  float*  s2_g     = (float*)(ws + 2710016);      // 266240 B
  float*  w_g      = (float*)(ws + 2976256);      // 266240 B
  float2* partials = (float2*)(ws + 3242496);     // 128*16*8 = 16384 B
  // total ws use: 3,258,880 bytes

  hipLaunchKernelGGL(k2_scores, dim3(NCHUNK, NBH), dim3(256), 0, stream,
                     query, key, s_key_cpu, logmask, scores, tk, partials);
  hipLaunchKernelGGL(k3_topk, dim3(NBH), dim3(256), 0, stream,
                     tk, indices);
  hipLaunchKernelGGL(k5_qk, dim3(26, NBH), dim3(256), 0, stream,
                     query, key, logmask, key_cpu, indices, s2_g);
  hipLaunchKernelGGL(k6_stats, dim3(128), dim3(256), 0, stream,
                     scores, partials, indices, s2_g, value, mean_v,
                     out_w, w_g, out);
  hipLaunchKernelGGL(k7_wv, dim3(17, NBH), dim3(256), 0, stream,
                     value, value_cpu, indices, w_g, out);
}